// Round 8
// baseline (1481.932 us; speedup 1.0000x reference)
//
#include <hip/hip_runtime.h>

// ---------------- problem constants ----------------
constexpr int NB  = 4;
constexpr int IH  = 270;
constexpr int IW  = 512;
constexpr int NPIX = IH * IW;      // 138240
constexpr int PH  = 271;           // pooled height
constexpr int PW  = 513;           // pooled width
constexpr float TWO_PI_F = 6.28318530717958647692f;

typedef short  bf16x8 __attribute__((ext_vector_type(8)));
typedef float floatx4 __attribute__((ext_vector_type(4)));

__device__ inline unsigned short f2bf(float x) {
  union { float f; unsigned u; } un; un.f = x;
  unsigned r = un.u + 0x7fff + ((un.u >> 16) & 1);   // RNE
  return (unsigned short)(r >> 16);
}
__device__ inline float bf2f(unsigned short u) {
  union { unsigned u; float f; } x; x.u = ((unsigned)u) << 16; return x.f;
}
// monotone float<->uint keys for atomic min/max
__device__ inline unsigned fkey(float f) {
  unsigned u = __float_as_uint(f);
  return (u & 0x80000000u) ? ~u : (u | 0x80000000u);
}
__device__ inline float funkey(unsigned k) {
  unsigned u = (k & 0x80000000u) ? (k ^ 0x80000000u) : ~k;
  return __uint_as_float(u);
}
// per-thread GN coef (thread c < C): A,B from fp32 stats
__device__ inline void gn_coef_thread(const float* __restrict__ stats,
                                      const float* __restrict__ gamma,
                                      const float* __restrict__ beta,
                                      float* cA, float* cB, int C, int chper, int b) {
  int c = threadIdx.x;
  if (c < C) {
    int g0 = (c / chper) * chper;
    float S = 0.f, S2 = 0.f;
    for (int k = 0; k < chper; k++) {
      S  += stats[(b * C + g0 + k) * 2];
      S2 += stats[(b * C + g0 + k) * 2 + 1];
    }
    double Nd = (double)chper * NPIX;
    double mu = (double)S / Nd;
    double var = (double)S2 / Nd - mu * mu;
    double rstd = 1.0 / sqrt(var + 1e-5);
    float A = (float)rstd * gamma[c];
    cA[c] = A;
    cB[c] = beta[c] - (float)mu * A;
  }
}

// ============================================================
// Combined weight prep: all MFMA B-packs + fp32 repacks, one kernel.
// ============================================================
__device__ inline void mfma_pack_one(const float* __restrict__ w, short* __restrict__ wB,
                                     int i, int CO, int CI, int KK, int CHUNKS) {
  int j = i & 7, l = (i >> 3) & 63, f = i >> 9;
  int t = f % KK; int fc = f / KK; int cc = fc % CHUNKS; int g = fc / CHUNKS;
  int ci = cc * 32 + ((l >> 4) << 3) + j;
  int co = g * 16 + (l & 15);
  float v = (ci < CI && co < CO) ? w[((size_t)co * CI + ci) * KK + t] : 0.f;
  wB[i] = (short)f2bf(v);
}
__device__ inline void repack_one(const float* __restrict__ w, float* __restrict__ wT,
                                  int i, int CO, int CI, int KK) {
  int o = i / (CI * KK);
  int r = i % (CI * KK);
  int ci = r / KK, kk = r % KK;
  wT[(kk * CI + ci) * CO + o] = w[i];
}
__global__ __launch_bounds__(256) void prep_kernel(
    const float* __restrict__ w1, const float* __restrict__ w2,
    const float* __restrict__ w3, const float* __restrict__ w4,
    const float* __restrict__ w5,
    short* __restrict__ w1B, short* __restrict__ w2B, short* __restrict__ w3B,
    float* __restrict__ w4T, float* __restrict__ w5T) {
  constexpr int N1 = 4 * 4 * 25 * 512;   // 204800
  constexpr int N2 = 2 * 2 * 9 * 512;    // 18432
  constexpr int N3 = 1 * 1 * 9 * 512;    // 4608
  constexpr int N4 = 8 * 16 * 9;         // 1152
  constexpr int N5 = 2 * 8 * 9;          // 144
  int i = blockIdx.x * 256 + threadIdx.x;
  if (i < N1) { mfma_pack_one(w1, w1B, i, 64, 128, 25, 4); return; }
  i -= N1;
  if (i < N2) { mfma_pack_one(w2, w2B, i, 32, 64, 9, 2); return; }
  i -= N2;
  if (i < N3) { mfma_pack_one(w3, w3B, i, 16, 32, 9, 1); return; }
  i -= N3;
  if (i < N4) { repack_one(w4, w4T, i, 8, 16, 9); return; }
  i -= N4;
  if (i < N5) { repack_one(w5, w5T, i, 2, 8, 9); return; }
}

// ============================================================
// Fused SIFT front-end: x -> full 128-ch bf16 descriptor, chunk-major
// descg[b][cc][pixel][32ch]. 16x16 tile; grid (32,17,NB), block 256.
// ============================================================
__global__ __launch_bounds__(256) void sift_desc_kernel(
    const float* __restrict__ x, short* __restrict__ descg) {
  const int b = blockIdx.z;
  const int x0 = blockIdx.x * 16, y0 = blockIdx.y * 16;
  __shared__ float xs[24][25];
  __shared__ float wo0[22][23], wo1[22][23];
  __shared__ int   bo0[22][23];
  __shared__ float pooled[8][19][20];
  __shared__ float s1s[256], gs[256];
  const int tid = threadIdx.x;
  const float* xb = x + (size_t)b * NPIX;

  for (int t = tid; t < 576; t += 256) {
    int r = t / 24, c = t % 24;
    int gy = min(max(y0 - 4 + r, 0), IH - 1);
    int gx = min(max(x0 - 4 + c, 0), IW - 1);
    xs[r][c] = xb[gy * IW + gx];
  }
  __syncthreads();

  for (int t = tid; t < 484; t += 256) {
    int r = t / 22, c = t % 22;
    int gy = y0 - 3 + r, gx = x0 - 3 + c;
    float w0 = 0.f, w1v = 0.f; int b0 = 0;
    if (gy >= 0 && gy < IH && gx >= 0 && gx < IW) {
      float gxv = (xs[r + 1][c + 2] - xs[r + 1][c]) * 0.5f;
      float gyv = (xs[r + 2][c + 1] - xs[r][c + 1]) * 0.5f;
      float mag = sqrtf(gxv * gxv + gyv * gyv + 1e-10f);
      float ori = atan2f(gyv, gxv + 1e-10f) + TWO_PI_F;
      float obig = ori * (8.0f / TWO_PI_F);
      float bf = floorf(obig);
      float w1_ = obig - bf;
      w0  = (1.0f - w1_) * mag;
      w1v = w1_ * mag;
      b0  = ((int)bf) & 7;
    }
    wo0[r][c] = w0; wo1[r][c] = w1v; bo0[r][c] = b0;
  }
  __syncthreads();

  const float pwt[4] = {0.25f, 0.75f, 0.75f, 0.25f};
  for (int t = tid; t < 361; t += 256) {
    int pr = t / 19, pc = t % 19;
    int py = y0 - 1 + pr, px = x0 - 1 + pc;
    float acc[8] = {0, 0, 0, 0, 0, 0, 0, 0};
    if (py >= 0 && py < PH && px >= 0 && px < PW) {
      #pragma unroll
      for (int i = 0; i < 4; i++) {
        #pragma unroll
        for (int j = 0; j < 4; j++) {
          float w0 = wo0[pr + i][pc + j], w1v = wo1[pr + i][pc + j];
          int b0 = bo0[pr + i][pc + j];
          int b1i = (b0 + 1) & 7;
          float pw = pwt[i] * pwt[j];
          #pragma unroll
          for (int a = 0; a < 8; a++) {
            float add = (a == b0 ? w0 : 0.f) + (a == b1i ? w1v : 0.f);
            acc[a] = fmaf(pw, add, acc[a]);
          }
        }
      }
    }
    #pragma unroll
    for (int a = 0; a < 8; a++) pooled[a][pr][pc] = acc[a];
  }
  __syncthreads();

  {
    int py = tid >> 4, px = tid & 15;
    int y = y0 + py;
    float s1 = 0.f, g = 0.f;
    if (y < IH) {
      float sum2 = 0.f;
      for (int c = 0; c < 128; c++) {
        int a = c >> 4, i = (c >> 2) & 3, j = c & 3;
        float p = pooled[a][py + i][px + j];
        sum2 = fmaf(p, p, sum2);
      }
      s1 = 1.0f / fmaxf(sqrtf(sum2), 1e-12f);
      float st2 = 0.f, st = 0.f;
      for (int c = 0; c < 128; c++) {
        int a = c >> 4, i = (c >> 2) & 3, j = c & 3;
        float p = pooled[a][py + i][px + j];
        float tv = fminf(p * s1, 0.2f);
        st2 = fmaf(tv, tv, st2);
        st += tv;
      }
      float s2 = 1.0f / fmaxf(sqrtf(st2), 1e-12f);
      float l1 = fmaxf(s2 * st, 1e-12f);
      g = s2 / l1;
    }
    s1s[tid] = s1; gs[tid] = g;
  }
  __syncthreads();

  for (int k = 0; k < 16; k++) {
    int gidx = k * 256 + tid;
    int cc = gidx >> 10, pix = (gidx >> 2) & 255, sub = gidx & 3;
    int py = pix >> 4, px = pix & 15;
    int y = y0 + py;
    if (y >= IH) continue;
    float s1v = s1s[pix], gv = gs[pix];
    int a = cc * 2 + (sub >> 1);
    unsigned short v8[8];
    #pragma unroll
    for (int jj = 0; jj < 8; jj++) {
      int i = (sub * 2 + (jj >> 2)) & 3;
      int j = jj & 3;
      float p = pooled[a][py + i][px + j];
      v8[jj] = f2bf(sqrtf(fminf(p * s1v, 0.2f) * gv + 1e-10f));
    }
    uint4 pk;
    pk.x = (unsigned)v8[0] | ((unsigned)v8[1] << 16);
    pk.y = (unsigned)v8[2] | ((unsigned)v8[3] << 16);
    pk.z = (unsigned)v8[4] | ((unsigned)v8[5] << 16);
    pk.w = (unsigned)v8[6] | ((unsigned)v8[7] << 16);
    size_t base = ((size_t)(b * 4 + cc) * NPIX + (size_t)y * IW + (x0 + px)) * 32 + sub * 8;
    *(uint4*)(descg + base) = pk;
  }
}

// ============================================================
// Conv1 via MFMA, 16x16 tile, 512-thread block (8 waves). Wave w:
// m-tiles (w>>1)*4+{0..3}, n-groups (w&1)*2+{0,1}. acc = 32 regs/wave
// -> 4 waves/SIMD (16 waves/CU) with __launch_bounds__(512,4).
// B prefetched one tap ahead (L2 latency); A direct from LDS (TLP covers).
// grid (32,17,NB), block 512.
// ============================================================
__global__ __launch_bounds__(512, 4) void conv1_mfma_kernel(
    const short* __restrict__ descg, const short* __restrict__ w1B,
    const float* __restrict__ bias, unsigned short* __restrict__ out,
    float* __restrict__ stats) {
  const int b = blockIdx.z;
  const int x0 = blockIdx.x * 16, y0 = blockIdx.y * 16;
  __shared__ __align__(16) char smem_raw[33408];
  short* desc = (short*)smem_raw;                 // [400 pos][40] bf16
  float* cout = (float*)smem_raw;                 // epilogue [32][261]

  const int tid = threadIdx.x;
  const int wave = tid >> 6, lane = tid & 63;
  const int quad = lane >> 4, lm = lane & 15;
  const int nh = wave & 1, mh = wave >> 1;        // nh 0..1, mh 0..3

  floatx4 acc[2][4];   // [n][m]
  #pragma unroll
  for (int j = 0; j < 2; j++)
    #pragma unroll
    for (int i = 0; i < 4; i++) acc[j][i] = (floatx4){0.f, 0.f, 0.f, 0.f};

  for (int cc = 0; cc < 4; cc++) {
    __syncthreads();   // previous chunk consumed
    const short* dg = descg + (size_t)(b * 4 + cc) * NPIX * 32;
    for (int u = tid; u < 1600; u += 512) {        // 400 pos x 4 16B-subs
      int pos = u >> 2, sub = u & 3;
      int r = pos / 20, c = pos % 20;
      int gy = y0 - 2 + r, gx = x0 - 2 + c;
      uint4 val = {0u, 0u, 0u, 0u};
      if (gy >= 0 && gy < IH && gx >= 0 && gx < IW)
        val = *(const uint4*)(dg + ((size_t)gy * IW + gx) * 32 + sub * 8);
      *(uint4*)(desc + pos * 40 + sub * 8) = val;
    }
    __syncthreads();   // desc ready

    const short* wb = w1B + (size_t)cc * 25 * 512 + (lane << 3);
    bf16x8 bfrC[2], bfrN[2];
    #pragma unroll
    for (int j = 0; j < 2; j++)
      bfrN[j] = *(const bf16x8*)(wb + (size_t)(nh * 2 + j) * 100 * 512);
    #pragma unroll
    for (int t = 0; t < 25; t++) {
      int ky = t / 5, kx = t % 5;
      #pragma unroll
      for (int j = 0; j < 2; j++) bfrC[j] = bfrN[j];
      if (t < 24) {
        int t1 = t + 1;
        #pragma unroll
        for (int j = 0; j < 2; j++)
          bfrN[j] = *(const bf16x8*)(wb + ((size_t)(nh * 2 + j) * 100 + t1) * 512);
      }
      bf16x8 av[4];
      #pragma unroll
      for (int i = 0; i < 4; i++)
        av[i] = *(const bf16x8*)(desc + ((mh * 4 + i + ky) * 20 + lm + kx) * 40 + quad * 8);
      #pragma unroll
      for (int j = 0; j < 2; j++)
        #pragma unroll
        for (int i = 0; i < 4; i++)
          acc[j][i] = __builtin_amdgcn_mfma_f32_16x16x32_bf16(av[i], bfrC[j], acc[j][i], 0, 0, 0);
    }
  }

  // epilogue in two 32-co halves: waves with nh==h own the half.
  unsigned short* ob = out + (size_t)b * 64 * NPIX;
  for (int h = 0; h < 2; h++) {
    __syncthreads();
    if (nh == h) {
      #pragma unroll
      for (int j = 0; j < 2; j++)
        #pragma unroll
        for (int i = 0; i < 4; i++)
          #pragma unroll
          for (int r = 0; r < 4; r++)
            cout[(j * 16 + lm) * 261 + (mh * 4 + i) * 16 + quad * 4 + r] = acc[j][i][r];
    }
    __syncthreads();
    for (int v = tid; v < 8192; v += 512) {
      int col = v >> 8, px = v & 255;
      int y = y0 + (px >> 4), x = x0 + (px & 15);
      if (y < IH)
        ob[(size_t)(h * 32 + col) * NPIX + y * IW + x] = f2bf(cout[col * 261 + px] + bias[h * 32 + col]);
    }
    // stats: 32 co x 16 segs (1 row each)
    int col = tid >> 4, seg = tid & 15;
    int co = h * 32 + col;
    float bv = bias[co];
    float sum = 0.f, sq = 0.f;
    if (y0 + seg < IH) {
      #pragma unroll
      for (int k = 0; k < 16; k++) {
        float vv = cout[col * 261 + seg * 16 + k] + bv;
        sum += vv; sq += vv * vv;
      }
    }
    sum += __shfl_down(sum, 8, 16); sq += __shfl_down(sq, 8, 16);
    sum += __shfl_down(sum, 4, 16); sq += __shfl_down(sq, 4, 16);
    sum += __shfl_down(sum, 2, 16); sq += __shfl_down(sq, 2, 16);
    sum += __shfl_down(sum, 1, 16); sq += __shfl_down(sq, 1, 16);
    if (seg == 0) {
      atomicAdd(&stats[(b * 64 + co) * 2], sum);
      atomicAdd(&stats[(b * 64 + co) * 2 + 1], sq);
    }
  }
}

// ============================================================
// 3x3 conv via MFMA, 16x8 tile, bf16 in/out, fused input-GN + output
// stats, one-tap-ahead software pipelining. grid (32,34,NB).
// ============================================================
template <int CI, int CO, int CHPER, bool STATS>
__global__ __launch_bounds__(256) void convk3_mfma_kernel(
    const unsigned short* __restrict__ xin, const short* __restrict__ wB,
    const float* __restrict__ bias, const float* __restrict__ statsIn,
    const float* __restrict__ gamma, const float* __restrict__ beta,
    float* __restrict__ statsOut, unsigned short* __restrict__ out) {
  constexpr int CHUNKS = CI / 32;
  constexpr int G = CO / 16;           // co-groups (2 or 1)
  constexpr int MPW = 2 * G;           // m-tiles per wave (4 or 2)
  constexpr int CIS = CI + 8;          // LDS short-stride per position
  constexpr int TILE_B = 180 * CIS * 2;
  constexpr int COUT_B = CO * 133 * 4;
  constexpr int UNION_B = TILE_B > COUT_B ? TILE_B : COUT_B;
  __shared__ __align__(16) char sm[UNION_B + CI * 8];
  short* tile = (short*)sm;
  float* cout = (float*)sm;
  float* cA = (float*)(sm + UNION_B);
  float* cB = cA + CI;

  const int b = blockIdx.z;
  const int x0 = blockIdx.x * 16, y0 = blockIdx.y * 8;
  const int tid = threadIdx.x;
  const int wave = tid >> 6, lane = tid & 63;
  const int quad = lane >> 4, lm = lane & 15;
  const int n = wave % G, mh = wave / G;

  gn_coef_thread(statsIn, gamma, beta, cA, cB, CI, CHPER, b);
  __syncthreads();

  const unsigned short* xb = xin + (size_t)b * CI * NPIX;
  for (int v = tid; v < (CI / 2) * 180; v += 256) {
    int cp = v / 180, pos = v % 180;
    int r = pos / 18, c = pos % 18;
    int gy = y0 - 1 + r, gx = x0 - 1 + c;
    float v0 = 0.f, v1 = 0.f;
    if (gy >= 0 && gy < IH && gx >= 0 && gx < IW) {
      v0 = fmaxf(fmaf(bf2f(xb[(size_t)(2 * cp) * NPIX + gy * IW + gx]), cA[2 * cp], cB[2 * cp]), 0.f);
      v1 = fmaxf(fmaf(bf2f(xb[(size_t)(2 * cp + 1) * NPIX + gy * IW + gx]), cA[2 * cp + 1], cB[2 * cp + 1]), 0.f);
    }
    unsigned pk = (unsigned)f2bf(v0) | ((unsigned)f2bf(v1) << 16);
    *(unsigned*)(tile + pos * CIS + 2 * cp) = pk;
  }
  __syncthreads();

  floatx4 acc[MPW];
  #pragma unroll
  for (int i = 0; i < MPW; i++) acc[i] = (floatx4){0.f, 0.f, 0.f, 0.f};

  constexpr int NT = CHUNKS * 9;
  const short* wbase = wB + ((size_t)n * NT) * 512 + (lane << 3);
  bf16x8 bfrC, avC[MPW], bfrN, avN[MPW];
  bfrN = *(const bf16x8*)(wbase);
  #pragma unroll
  for (int i = 0; i < MPW; i++)
    avN[i] = *(const bf16x8*)(tile + ((mh * MPW + i) * 18 + lm) * CIS + quad * 8);
  #pragma unroll
  for (int t = 0; t < NT; t++) {
    bfrC = bfrN;
    #pragma unroll
    for (int i = 0; i < MPW; i++) avC[i] = avN[i];
    if (t < NT - 1) {
      int t1 = t + 1;
      int cc1 = t1 / 9, r1 = t1 % 9, ky1 = r1 / 3, kx1 = r1 % 3;
      bfrN = *(const bf16x8*)(wbase + (size_t)t1 * 512);
      #pragma unroll
      for (int i = 0; i < MPW; i++)
        avN[i] = *(const bf16x8*)(tile + ((mh * MPW + i + ky1) * 18 + lm + kx1) * CIS + cc1 * 32 + quad * 8);
    }
    #pragma unroll
    for (int i = 0; i < MPW; i++)
      acc[i] = __builtin_amdgcn_mfma_f32_16x16x32_bf16(avC[i], bfrC, acc[i], 0, 0, 0);
  }
  __syncthreads();   // tile consumed; cout overlays
  #pragma unroll
  for (int i = 0; i < MPW; i++) {
    #pragma unroll
    for (int r = 0; r < 4; r++) {
      int pixel = (mh * MPW + i) * 16 + quad * 4 + r;
      cout[(n * 16 + lm) * 133 + pixel] = acc[i][r];
    }
  }
  __syncthreads();
  unsigned short* ob = out + (size_t)b * CO * NPIX;
  for (int v = tid; v < CO * 128; v += 256) {
    int co = v >> 7, px = v & 127;
    int y = y0 + (px >> 4), x = x0 + (px & 15);
    if (y < IH) ob[(size_t)co * NPIX + y * IW + x] = f2bf(cout[co * 133 + px] + bias[co]);
  }
  if (STATS) {
    constexpr int TPC = 256 / CO;     // threads per channel (8 or 16)
    constexpr int PXT = 128 / TPC;    // pixels per thread
    int col = tid / TPC, seg = tid % TPC;
    float bv = bias[col];
    float sum = 0.f, sq = 0.f;
    #pragma unroll
    for (int k = 0; k < PXT; k++) {
      int p = seg * PXT + k;
      if (y0 + (p >> 4) < IH) {
        float vv = cout[col * 133 + p] + bv;
        sum += vv; sq += vv * vv;
      }
    }
    #pragma unroll
    for (int off = TPC / 2; off > 0; off >>= 1) {
      sum += __shfl_down(sum, off);
      sq  += __shfl_down(sq, off);
    }
    if (seg == 0) {
      atomicAdd(&statsOut[(b * CO + col) * 2], sum);
      atomicAdd(&statsOut[(b * CO + col) * 2 + 1], sq);
    }
  }
}

// ============================================================
// Small direct fp32 3x3 conv, 16x8 tile, bf16 input + fused GN, output
// bf16 (OUT_BF16) or fp32, optional output stats via LDS atomics.
// ============================================================
template <int CI, int CO, int CHPER, bool STATS, bool OUT_BF16>
__global__ __launch_bounds__(256) void convs_kernel(
    const unsigned short* __restrict__ xin, const float* __restrict__ wT,
    const float* __restrict__ bias, const float* __restrict__ statsIn,
    const float* __restrict__ gamma, const float* __restrict__ beta,
    float* __restrict__ statsOut, void* __restrict__ outv) {
  constexpr int OPT = CO / 2;
  const int b = blockIdx.z;
  const int x0 = blockIdx.x * 16, y0 = blockIdx.y * 8;
  __shared__ float tile[CI * 180];
  __shared__ float cA[CI], cB[CI];
  __shared__ float ssum[CO], ssq[CO];
  gn_coef_thread(statsIn, gamma, beta, cA, cB, CI, CHPER, b);
  if (STATS && threadIdx.x < CO) { ssum[threadIdx.x] = 0.f; ssq[threadIdx.x] = 0.f; }
  __syncthreads();
  const unsigned short* xb = xin + (size_t)b * CI * NPIX;
  for (int t = threadIdx.x; t < CI * 180; t += 256) {
    int ci = t / 180, rc = t % 180, r = rc / 18, c = rc % 18;
    int gy = y0 - 1 + r, gx = x0 - 1 + c;
    float v = 0.f;
    if (gy >= 0 && gy < IH && gx >= 0 && gx < IW)
      v = fmaxf(fmaf(bf2f(xb[(size_t)ci * NPIX + gy * IW + gx]), cA[ci], cB[ci]), 0.f);
    tile[t] = v;
  }
  __syncthreads();
  const int t = threadIdx.x;
  const int px = t & 127, og = t >> 7;
  const int pyy = px >> 4, pxx = px & 15;
  const int oc0 = og * OPT;
  const int y = y0 + pyy, x = x0 + pxx;
  float acc[OPT] = {};
  for (int ky = 0; ky < 3; ky++) {
    for (int kx = 0; kx < 3; kx++) {
      const float* wrow = wT + (size_t)((ky * 3 + kx) * CI) * CO + oc0;
      for (int ci = 0; ci < CI; ci++) {
        float v = tile[ci * 180 + (pyy + ky) * 18 + pxx + kx];
        #pragma unroll
        for (int o = 0; o < OPT; o++) acc[o] = fmaf(v, wrow[ci * CO + o], acc[o]);
      }
    }
  }
  if (y < IH) {
    #pragma unroll
    for (int o = 0; o < OPT; o++) {
      float vv = acc[o] + bias[oc0 + o];
      if (OUT_BF16) {
        unsigned short* ob = (unsigned short*)outv + (size_t)b * CO * NPIX;
        ob[(size_t)(oc0 + o) * NPIX + y * IW + x] = f2bf(vv);
      } else {
        float* ob = (float*)outv + (size_t)b * CO * NPIX;
        ob[(size_t)(oc0 + o) * NPIX + y * IW + x] = vv;
      }
      if (STATS) {
        atomicAdd(&ssum[oc0 + o], vv);
        atomicAdd(&ssq[oc0 + o], vv * vv);
      }
    }
  }
  if (STATS) {
    __syncthreads();
    if (threadIdx.x < CO) {
      atomicAdd(&statsOut[(b * CO + threadIdx.x) * 2], ssum[threadIdx.x]);
      atomicAdd(&statsOut[(b * CO + threadIdx.x) * 2 + 1], ssq[threadIdx.x]);
    }
  }
}

// ============================================================
// Joint bilateral 5x5 (reflect), guide fused, global min/max fused.
// ============================================================
__global__ __launch_bounds__(256) void bilateral_kernel(
    const float* __restrict__ f, const float* __restrict__ gt,
    float* __restrict__ out, unsigned* __restrict__ mmbits) {
  const int b = blockIdx.z;
  const int x0 = blockIdx.x * 16, y0 = blockIdx.y * 16;
  __shared__ float gu[20][20], gv[20][20], f0s[20][20], f1s[20][20];
  __shared__ float red[4][4];
  const float* gtb = gt + (size_t)b * 3 * NPIX;
  const float* fb = f + (size_t)b * 2 * NPIX;
  for (int t = threadIdx.x; t < 400; t += 256) {
    int r = t / 20, c = t % 20;
    int gy = y0 - 2 + r, gx = x0 - 2 + c;
    if (gy < 0) gy = -gy;
    if (gy > IH - 1) gy = 2 * (IH - 1) - gy;
    if (gx < 0) gx = -gx;
    if (gx > IW - 1) gx = 2 * (IW - 1) - gx;
    int p = gy * IW + gx;
    float rr = gtb[p], gg = gtb[NPIX + p], bb = gtb[2 * NPIX + p];
    gu[r][c]  = -0.147f * rr - 0.289f * gg + 0.436f * bb;
    gv[r][c]  =  0.615f * rr - 0.515f * gg - 0.100f * bb;
    f0s[r][c] = fb[p];
    f1s[r][c] = fb[NPIX + p];
  }
  __syncthreads();
  const int t = threadIdx.x;
  const int lx = t % 16, ly = t / 16;
  const int y = y0 + ly, x = x0 + lx;
  const bool valid = (y < IH);

  float o0 = 0.f, o1 = 0.f;
  if (valid) {
    float g1v[5];
    float s = 0.f;
    #pragma unroll
    for (int k = 0; k < 5; k++) {
      float a = (float)(k - 2);
      g1v[k] = expf(-a * a / 4.5f);
      s += g1v[k];
    }
    #pragma unroll
    for (int k = 0; k < 5; k++) g1v[k] /= s;
    float cu = gu[ly + 2][lx + 2], cv = gv[ly + 2][lx + 2];
    float num0 = 0.f, num1 = 0.f, den = 0.f;
    #pragma unroll
    for (int dy = 0; dy < 5; dy++) {
      #pragma unroll
      for (int dx = 0; dx < 5; dx++) {
        float du = fabsf(gu[ly + dy][lx + dx] - cu) + fabsf(gv[ly + dy][lx + dx] - cv);
        float wgt = g1v[dy] * g1v[dx] * expf(-50.0f * du * du);
        num0 = fmaf(wgt, f0s[ly + dy][lx + dx], num0);
        num1 = fmaf(wgt, f1s[ly + dy][lx + dx], num1);
        den += wgt;
      }
    }
    o0 = num0 / den; o1 = num1 / den;
    float* ob = out + (size_t)b * 2 * NPIX;
    ob[y * IW + x] = o0;
    ob[NPIX + y * IW + x] = o1;
  }
  float mn0 = valid ? o0 : 1e30f,  mx0 = valid ? o0 : -1e30f;
  float mn1 = valid ? o1 : 1e30f,  mx1 = valid ? o1 : -1e30f;
  #pragma unroll
  for (int off = 32; off > 0; off >>= 1) {
    mn0 = fminf(mn0, __shfl_xor(mn0, off));
    mx0 = fmaxf(mx0, __shfl_xor(mx0, off));
    mn1 = fminf(mn1, __shfl_xor(mn1, off));
    mx1 = fmaxf(mx1, __shfl_xor(mx1, off));
  }
  if ((t & 63) == 0) {
    red[t >> 6][0] = mn0; red[t >> 6][1] = mx0;
    red[t >> 6][2] = mn1; red[t >> 6][3] = mx1;
  }
  __syncthreads();
  if (t == 0) {
    for (int w = 1; w < 4; w++) {
      red[0][0] = fminf(red[0][0], red[w][0]);
      red[0][1] = fmaxf(red[0][1], red[w][1]);
      red[0][2] = fminf(red[0][2], red[w][2]);
      red[0][3] = fmaxf(red[0][3], red[w][3]);
    }
    atomicMax(&mmbits[0], fkey(red[0][1]));   // max0
    atomicMax(&mmbits[1], fkey(red[0][3]));   // max1
    atomicMin(&mmbits[2], fkey(red[0][0]));   // min0
    atomicMin(&mmbits[3], fkey(red[0][2]));   // min1
  }
}

// ============================================================
// Final: rescale U/V from atomic min/max keys, YUV->RGB
// ============================================================
__global__ __launch_bounds__(256) void final_kernel(
    const float* __restrict__ bil, const float* __restrict__ x,
    const unsigned* __restrict__ mmbits, float* __restrict__ out) {
  int i = blockIdx.x * 256 + threadIdx.x;
  if (i >= NB * NPIX) return;
  float mx0 = funkey(mmbits[0]), mx1 = funkey(mmbits[1]);
  float mn0 = funkey(mmbits[2]), mn1 = funkey(mmbits[3]);
  int b = i / NPIX, p = i % NPIX;
  float f0 = bil[(size_t)b * 2 * NPIX + p];
  float f1 = bil[(size_t)b * 2 * NPIX + NPIX + p];
  float U = (f0 - mn0) / (mx0 - mn0 + 1e-6f);
  U = fminf(fmaxf(U, 0.f), 1.f) * 0.872f - 0.436f;
  float V = (f1 - mn1) / (mx1 - mn1 + 1e-6f);
  V = fminf(fmaxf(V, 0.f), 1.f) * 1.23f - 0.615f;
  float Y = x[(size_t)b * NPIX + p];
  float* ob = out + (size_t)b * 3 * NPIX;
  ob[p]            = Y + 1.14f * V;
  ob[NPIX + p]     = Y - 0.396f * U - 0.581f * V;
  ob[2 * NPIX + p] = Y + 2.029f * U;
}

// ============================================================
// launch
// ============================================================
extern "C" void kernel_launch(void* const* d_in, const int* in_sizes, int n_in,
                              void* d_out, int out_size, void* d_ws, size_t ws_size,
                              hipStream_t stream) {
  const float* x   = (const float*)d_in[0];
  const float* gt  = (const float*)d_in[1];
  const float* w1  = (const float*)d_in[2];
  const float* b1  = (const float*)d_in[3];
  const float* g1w = (const float*)d_in[4];
  const float* g1b = (const float*)d_in[5];
  const float* w2  = (const float*)d_in[6];
  const float* b2  = (const float*)d_in[7];
  const float* g2w = (const float*)d_in[8];
  const float* g2b = (const float*)d_in[9];
  const float* w3  = (const float*)d_in[10];
  const float* b3  = (const float*)d_in[11];
  const float* g3w = (const float*)d_in[12];
  const float* g3b = (const float*)d_in[13];
  const float* w4  = (const float*)d_in[14];
  const float* b4  = (const float*)d_in[15];
  const float* g4w = (const float*)d_in[16];
  const float* g4b = (const float*)d_in[17];
  const float* w5  = (const float*)d_in[18];
  const float* b5  = (const float*)d_in[19];
  float* out = (float*)d_out;

  // ---- workspace layout ----
  char* ws = (char*)d_ws;
  float* stats1 = (float*)ws;                  // 512
  float* stats2 = stats1 + 512;                // 256
  float* stats3 = stats2 + 256;                // 128
  float* stats4 = stats3 + 128;                // 64  (ends 960)
  unsigned* mmbits = (unsigned*)(ws + 12288);  // [max0,max1,min0,min1]
  char* base = ws + 16384;
  short* descg = (short*)base;
  size_t descg_shorts = (size_t)NB * 4 * NPIX * 32;       // 70,778,880
  unsigned short* bufB_h = (unsigned short*)base;         // conv2 out 32ch / conv4 out 8ch
  float* c5    = (float*)(base + 36000000);               // conv5 out (2ch fp32)
  float* bilat = (float*)(base + 41000000);               // bilateral out
  short* w1B = descg + descg_shorts;                      // 204800 shorts
  short* w2B = w1B + 204800;                              // 18432
  short* w3B = w2B + 18432;                               // 4608
  float* w4T = (float*)(w3B + 4608);                      // 1152 floats
  float* w5T = w4T + 1152;                                // 144 floats
  unsigned short* bufA_h = (unsigned short*)(w5T + 144);  // conv1 out 64ch / conv3 out 16ch

  hipMemsetAsync(ws, 0, 12304, stream);              // stats + max keys
  hipMemsetAsync(ws + 12296, 0xFF, 8, stream);       // min keys

  prep_kernel<<<896, 256, 0, stream>>>(w1, w2, w3, w4, w5, w1B, w2B, w3B, w4T, w5T);

  sift_desc_kernel<<<dim3(32, 17, NB), 256, 0, stream>>>(x, descg);

  conv1_mfma_kernel<<<dim3(32, 17, NB), 512, 0, stream>>>(descg, w1B, b1, bufA_h, stats1);

  convk3_mfma_kernel<64, 32, 8, true><<<dim3(32, 34, NB), 256, 0, stream>>>(
      bufA_h, w2B, b2, stats1, g1w, g1b, stats2, bufB_h);

  convk3_mfma_kernel<32, 16, 4, true><<<dim3(32, 34, NB), 256, 0, stream>>>(
      bufB_h, w3B, b3, stats2, g2w, g2b, stats3, bufA_h);

  convs_kernel<16, 8, 4, true, true><<<dim3(32, 34, NB), 256, 0, stream>>>(
      bufA_h, w4T, b4, stats3, g3w, g3b, stats4, bufB_h);

  convs_kernel<8, 2, 2, false, false><<<dim3(32, 34, NB), 256, 0, stream>>>(
      bufB_h, w5T, b5, stats4, g4w, g4b, nullptr, c5);

  bilateral_kernel<<<dim3(32, 17, NB), 256, 0, stream>>>(c5, gt, bilat, mmbits);
  final_kernel<<<(NB * NPIX + 255) / 256, 256, 0, stream>>>(bilat, x, mmbits, out);

  (void)in_sizes; (void)n_in; (void)out_size; (void)ws_size;
}

// Round 9
// 1299.955 us; speedup vs baseline: 1.1400x; 1.1400x over previous
//
#include <hip/hip_runtime.h>

// ---------------- problem constants ----------------
constexpr int NB  = 4;
constexpr int IH  = 270;
constexpr int IW  = 512;
constexpr int NPIX = IH * IW;      // 138240
constexpr int PH  = 271;           // pooled height
constexpr int PW  = 513;           // pooled width
constexpr float TWO_PI_F = 6.28318530717958647692f;

typedef short  bf16x8 __attribute__((ext_vector_type(8)));
typedef float floatx4 __attribute__((ext_vector_type(4)));

__device__ inline unsigned short f2bf(float x) {
  union { float f; unsigned u; } un; un.f = x;
  unsigned r = un.u + 0x7fff + ((un.u >> 16) & 1);   // RNE
  return (unsigned short)(r >> 16);
}
__device__ inline float bf2f(unsigned short u) {
  union { unsigned u; float f; } x; x.u = ((unsigned)u) << 16; return x.f;
}
// monotone float<->uint keys for atomic min/max
__device__ inline unsigned fkey(float f) {
  unsigned u = __float_as_uint(f);
  return (u & 0x80000000u) ? ~u : (u | 0x80000000u);
}
__device__ inline float funkey(unsigned k) {
  unsigned u = (k & 0x80000000u) ? (k ^ 0x80000000u) : ~k;
  return __uint_as_float(u);
}
// per-thread GN coef (thread c < C): A,B from fp32 stats
__device__ inline void gn_coef_thread(const float* __restrict__ stats,
                                      const float* __restrict__ gamma,
                                      const float* __restrict__ beta,
                                      float* cA, float* cB, int C, int chper, int b) {
  int c = threadIdx.x;
  if (c < C) {
    int g0 = (c / chper) * chper;
    float S = 0.f, S2 = 0.f;
    for (int k = 0; k < chper; k++) {
      S  += stats[(b * C + g0 + k) * 2];
      S2 += stats[(b * C + g0 + k) * 2 + 1];
    }
    double Nd = (double)chper * NPIX;
    double mu = (double)S / Nd;
    double var = (double)S2 / Nd - mu * mu;
    double rstd = 1.0 / sqrt(var + 1e-5);
    float A = (float)rstd * gamma[c];
    cA[c] = A;
    cB[c] = beta[c] - (float)mu * A;
  }
}

// ============================================================
// Combined weight prep: all MFMA B-packs + fp32 repacks, one kernel.
// ============================================================
__device__ inline void mfma_pack_one(const float* __restrict__ w, short* __restrict__ wB,
                                     int i, int CO, int CI, int KK, int CHUNKS) {
  int j = i & 7, l = (i >> 3) & 63, f = i >> 9;
  int t = f % KK; int fc = f / KK; int cc = fc % CHUNKS; int g = fc / CHUNKS;
  int ci = cc * 32 + ((l >> 4) << 3) + j;
  int co = g * 16 + (l & 15);
  float v = (ci < CI && co < CO) ? w[((size_t)co * CI + ci) * KK + t] : 0.f;
  wB[i] = (short)f2bf(v);
}
__device__ inline void repack_one(const float* __restrict__ w, float* __restrict__ wT,
                                  int i, int CO, int CI, int KK) {
  int o = i / (CI * KK);
  int r = i % (CI * KK);
  int ci = r / KK, kk = r % KK;
  wT[(kk * CI + ci) * CO + o] = w[i];
}
__global__ __launch_bounds__(256) void prep_kernel(
    const float* __restrict__ w1, const float* __restrict__ w2,
    const float* __restrict__ w3, const float* __restrict__ w4,
    const float* __restrict__ w5,
    short* __restrict__ w1B, short* __restrict__ w2B, short* __restrict__ w3B,
    float* __restrict__ w4T, float* __restrict__ w5T) {
  constexpr int N1 = 4 * 4 * 25 * 512;   // 204800
  constexpr int N2 = 2 * 2 * 9 * 512;    // 18432
  constexpr int N3 = 1 * 1 * 9 * 512;    // 4608
  constexpr int N4 = 8 * 16 * 9;         // 1152
  constexpr int N5 = 2 * 8 * 9;          // 144
  int i = blockIdx.x * 256 + threadIdx.x;
  if (i < N1) { mfma_pack_one(w1, w1B, i, 64, 128, 25, 4); return; }
  i -= N1;
  if (i < N2) { mfma_pack_one(w2, w2B, i, 32, 64, 9, 2); return; }
  i -= N2;
  if (i < N3) { mfma_pack_one(w3, w3B, i, 16, 32, 9, 1); return; }
  i -= N3;
  if (i < N4) { repack_one(w4, w4T, i, 8, 16, 9); return; }
  i -= N4;
  if (i < N5) { repack_one(w5, w5T, i, 2, 8, 9); return; }
}

// ============================================================
// Fused SIFT front-end: x -> full 128-ch bf16 descriptor, chunk-major
// descg[b][cc][pixel][32ch]. 16x16 tile; grid (32,17,NB), block 256.
// ============================================================
__global__ __launch_bounds__(256) void sift_desc_kernel(
    const float* __restrict__ x, short* __restrict__ descg) {
  const int b = blockIdx.z;
  const int x0 = blockIdx.x * 16, y0 = blockIdx.y * 16;
  __shared__ float xs[24][25];
  __shared__ float wo0[22][23], wo1[22][23];
  __shared__ int   bo0[22][23];
  __shared__ float pooled[8][19][20];
  __shared__ float s1s[256], gs[256];
  const int tid = threadIdx.x;
  const float* xb = x + (size_t)b * NPIX;

  for (int t = tid; t < 576; t += 256) {
    int r = t / 24, c = t % 24;
    int gy = min(max(y0 - 4 + r, 0), IH - 1);
    int gx = min(max(x0 - 4 + c, 0), IW - 1);
    xs[r][c] = xb[gy * IW + gx];
  }
  __syncthreads();

  for (int t = tid; t < 484; t += 256) {
    int r = t / 22, c = t % 22;
    int gy = y0 - 3 + r, gx = x0 - 3 + c;
    float w0 = 0.f, w1v = 0.f; int b0 = 0;
    if (gy >= 0 && gy < IH && gx >= 0 && gx < IW) {
      float gxv = (xs[r + 1][c + 2] - xs[r + 1][c]) * 0.5f;
      float gyv = (xs[r + 2][c + 1] - xs[r][c + 1]) * 0.5f;
      float mag = sqrtf(gxv * gxv + gyv * gyv + 1e-10f);
      float ori = atan2f(gyv, gxv + 1e-10f) + TWO_PI_F;
      float obig = ori * (8.0f / TWO_PI_F);
      float bf = floorf(obig);
      float w1_ = obig - bf;
      w0  = (1.0f - w1_) * mag;
      w1v = w1_ * mag;
      b0  = ((int)bf) & 7;
    }
    wo0[r][c] = w0; wo1[r][c] = w1v; bo0[r][c] = b0;
  }
  __syncthreads();

  const float pwt[4] = {0.25f, 0.75f, 0.75f, 0.25f};
  for (int t = tid; t < 361; t += 256) {
    int pr = t / 19, pc = t % 19;
    int py = y0 - 1 + pr, px = x0 - 1 + pc;
    float acc[8] = {0, 0, 0, 0, 0, 0, 0, 0};
    if (py >= 0 && py < PH && px >= 0 && px < PW) {
      #pragma unroll
      for (int i = 0; i < 4; i++) {
        #pragma unroll
        for (int j = 0; j < 4; j++) {
          float w0 = wo0[pr + i][pc + j], w1v = wo1[pr + i][pc + j];
          int b0 = bo0[pr + i][pc + j];
          int b1i = (b0 + 1) & 7;
          float pw = pwt[i] * pwt[j];
          #pragma unroll
          for (int a = 0; a < 8; a++) {
            float add = (a == b0 ? w0 : 0.f) + (a == b1i ? w1v : 0.f);
            acc[a] = fmaf(pw, add, acc[a]);
          }
        }
      }
    }
    #pragma unroll
    for (int a = 0; a < 8; a++) pooled[a][pr][pc] = acc[a];
  }
  __syncthreads();

  {
    int py = tid >> 4, px = tid & 15;
    int y = y0 + py;
    float s1 = 0.f, g = 0.f;
    if (y < IH) {
      float sum2 = 0.f;
      for (int c = 0; c < 128; c++) {
        int a = c >> 4, i = (c >> 2) & 3, j = c & 3;
        float p = pooled[a][py + i][px + j];
        sum2 = fmaf(p, p, sum2);
      }
      s1 = 1.0f / fmaxf(sqrtf(sum2), 1e-12f);
      float st2 = 0.f, st = 0.f;
      for (int c = 0; c < 128; c++) {
        int a = c >> 4, i = (c >> 2) & 3, j = c & 3;
        float p = pooled[a][py + i][px + j];
        float tv = fminf(p * s1, 0.2f);
        st2 = fmaf(tv, tv, st2);
        st += tv;
      }
      float s2 = 1.0f / fmaxf(sqrtf(st2), 1e-12f);
      float l1 = fmaxf(s2 * st, 1e-12f);
      g = s2 / l1;
    }
    s1s[tid] = s1; gs[tid] = g;
  }
  __syncthreads();

  for (int k = 0; k < 16; k++) {
    int gidx = k * 256 + tid;
    int cc = gidx >> 10, pix = (gidx >> 2) & 255, sub = gidx & 3;
    int py = pix >> 4, px = pix & 15;
    int y = y0 + py;
    if (y >= IH) continue;
    float s1v = s1s[pix], gv = gs[pix];
    int a = cc * 2 + (sub >> 1);
    unsigned short v8[8];
    #pragma unroll
    for (int jj = 0; jj < 8; jj++) {
      int i = (sub * 2 + (jj >> 2)) & 3;
      int j = jj & 3;
      float p = pooled[a][py + i][px + j];
      v8[jj] = f2bf(sqrtf(fminf(p * s1v, 0.2f) * gv + 1e-10f));
    }
    uint4 pk;
    pk.x = (unsigned)v8[0] | ((unsigned)v8[1] << 16);
    pk.y = (unsigned)v8[2] | ((unsigned)v8[3] << 16);
    pk.z = (unsigned)v8[4] | ((unsigned)v8[5] << 16);
    pk.w = (unsigned)v8[6] | ((unsigned)v8[7] << 16);
    size_t base = ((size_t)(b * 4 + cc) * NPIX + (size_t)y * IW + (x0 + px)) * 32 + sub * 8;
    *(uint4*)(descg + base) = pk;
  }
}

// ============================================================
// Conv1 via MFMA, 16x16 tile, 512-thread block (8 waves). Wave w:
// m-tiles (w>>1)*4+{0..3}, n-groups (w&1)*2+{0,1}. acc = 32 regs/wave.
// __launch_bounds__(512, 2): min-waves=2 caps arch VGPR at 128 (fits the
// ~100-reg live set). min-waves=4 caps at 64 and SPILLS (R4/R8: FETCH
// 0.5 GB, WRITE 0.28 GB scratch traffic). HW co-residency: 2 blocks x 8
// waves = 4 waves/SIMD at ~132 total regs/wave.
// grid (32,17,NB), block 512.
// ============================================================
__global__ __launch_bounds__(512, 2) void conv1_mfma_kernel(
    const short* __restrict__ descg, const short* __restrict__ w1B,
    const float* __restrict__ bias, unsigned short* __restrict__ out,
    float* __restrict__ stats) {
  const int b = blockIdx.z;
  const int x0 = blockIdx.x * 16, y0 = blockIdx.y * 16;
  __shared__ __align__(16) char smem_raw[33408];
  short* desc = (short*)smem_raw;                 // [400 pos][40] bf16
  float* cout = (float*)smem_raw;                 // epilogue [32][261]

  const int tid = threadIdx.x;
  const int wave = tid >> 6, lane = tid & 63;
  const int quad = lane >> 4, lm = lane & 15;
  const int nh = wave & 1, mh = wave >> 1;        // nh 0..1, mh 0..3

  floatx4 acc[2][4];   // [n][m]
  #pragma unroll
  for (int j = 0; j < 2; j++)
    #pragma unroll
    for (int i = 0; i < 4; i++) acc[j][i] = (floatx4){0.f, 0.f, 0.f, 0.f};

  for (int cc = 0; cc < 4; cc++) {
    __syncthreads();   // previous chunk consumed
    const short* dg = descg + (size_t)(b * 4 + cc) * NPIX * 32;
    for (int u = tid; u < 1600; u += 512) {        // 400 pos x 4 16B-subs
      int pos = u >> 2, sub = u & 3;
      int r = pos / 20, c = pos % 20;
      int gy = y0 - 2 + r, gx = x0 - 2 + c;
      uint4 val = {0u, 0u, 0u, 0u};
      if (gy >= 0 && gy < IH && gx >= 0 && gx < IW)
        val = *(const uint4*)(dg + ((size_t)gy * IW + gx) * 32 + sub * 8);
      *(uint4*)(desc + pos * 40 + sub * 8) = val;
    }
    __syncthreads();   // desc ready

    const short* wb = w1B + (size_t)cc * 25 * 512 + (lane << 3);
    bf16x8 bfrC[2], bfrN[2];
    #pragma unroll
    for (int j = 0; j < 2; j++)
      bfrN[j] = *(const bf16x8*)(wb + (size_t)(nh * 2 + j) * 100 * 512);
    #pragma unroll
    for (int t = 0; t < 25; t++) {
      int ky = t / 5, kx = t % 5;
      #pragma unroll
      for (int j = 0; j < 2; j++) bfrC[j] = bfrN[j];
      if (t < 24) {
        int t1 = t + 1;
        #pragma unroll
        for (int j = 0; j < 2; j++)
          bfrN[j] = *(const bf16x8*)(wb + ((size_t)(nh * 2 + j) * 100 + t1) * 512);
      }
      bf16x8 av[4];
      #pragma unroll
      for (int i = 0; i < 4; i++)
        av[i] = *(const bf16x8*)(desc + ((mh * 4 + i + ky) * 20 + lm + kx) * 40 + quad * 8);
      #pragma unroll
      for (int j = 0; j < 2; j++)
        #pragma unroll
        for (int i = 0; i < 4; i++)
          acc[j][i] = __builtin_amdgcn_mfma_f32_16x16x32_bf16(av[i], bfrC[j], acc[j][i], 0, 0, 0);
    }
  }

  // epilogue in two 32-co halves: waves with nh==h own the half.
  unsigned short* ob = out + (size_t)b * 64 * NPIX;
  for (int h = 0; h < 2; h++) {
    __syncthreads();
    if (nh == h) {
      #pragma unroll
      for (int j = 0; j < 2; j++)
        #pragma unroll
        for (int i = 0; i < 4; i++)
          #pragma unroll
          for (int r = 0; r < 4; r++)
            cout[(j * 16 + lm) * 261 + (mh * 4 + i) * 16 + quad * 4 + r] = acc[j][i][r];
    }
    __syncthreads();
    for (int v = tid; v < 8192; v += 512) {
      int col = v >> 8, px = v & 255;
      int y = y0 + (px >> 4), x = x0 + (px & 15);
      if (y < IH)
        ob[(size_t)(h * 32 + col) * NPIX + y * IW + x] = f2bf(cout[col * 261 + px] + bias[h * 32 + col]);
    }
    // stats: 32 co x 16 segs (1 row each)
    int col = tid >> 4, seg = tid & 15;
    int co = h * 32 + col;
    float bv = bias[co];
    float sum = 0.f, sq = 0.f;
    if (y0 + seg < IH) {
      #pragma unroll
      for (int k = 0; k < 16; k++) {
        float vv = cout[col * 261 + seg * 16 + k] + bv;
        sum += vv; sq += vv * vv;
      }
    }
    sum += __shfl_down(sum, 8, 16); sq += __shfl_down(sq, 8, 16);
    sum += __shfl_down(sum, 4, 16); sq += __shfl_down(sq, 4, 16);
    sum += __shfl_down(sum, 2, 16); sq += __shfl_down(sq, 2, 16);
    sum += __shfl_down(sum, 1, 16); sq += __shfl_down(sq, 1, 16);
    if (seg == 0) {
      atomicAdd(&stats[(b * 64 + co) * 2], sum);
      atomicAdd(&stats[(b * 64 + co) * 2 + 1], sq);
    }
  }
}

// ============================================================
// 3x3 conv via MFMA, 16x8 tile, bf16 in/out, fused input-GN + output
// stats, one-tap-ahead software pipelining. grid (32,34,NB).
// ============================================================
template <int CI, int CO, int CHPER, bool STATS>
__global__ __launch_bounds__(256) void convk3_mfma_kernel(
    const unsigned short* __restrict__ xin, const short* __restrict__ wB,
    const float* __restrict__ bias, const float* __restrict__ statsIn,
    const float* __restrict__ gamma, const float* __restrict__ beta,
    float* __restrict__ statsOut, unsigned short* __restrict__ out) {
  constexpr int CHUNKS = CI / 32;
  constexpr int G = CO / 16;           // co-groups (2 or 1)
  constexpr int MPW = 2 * G;           // m-tiles per wave (4 or 2)
  constexpr int CIS = CI + 8;          // LDS short-stride per position
  constexpr int TILE_B = 180 * CIS * 2;
  constexpr int COUT_B = CO * 133 * 4;
  constexpr int UNION_B = TILE_B > COUT_B ? TILE_B : COUT_B;
  __shared__ __align__(16) char sm[UNION_B + CI * 8];
  short* tile = (short*)sm;
  float* cout = (float*)sm;
  float* cA = (float*)(sm + UNION_B);
  float* cB = cA + CI;

  const int b = blockIdx.z;
  const int x0 = blockIdx.x * 16, y0 = blockIdx.y * 8;
  const int tid = threadIdx.x;
  const int wave = tid >> 6, lane = tid & 63;
  const int quad = lane >> 4, lm = lane & 15;
  const int n = wave % G, mh = wave / G;

  gn_coef_thread(statsIn, gamma, beta, cA, cB, CI, CHPER, b);
  __syncthreads();

  const unsigned short* xb = xin + (size_t)b * CI * NPIX;
  for (int v = tid; v < (CI / 2) * 180; v += 256) {
    int cp = v / 180, pos = v % 180;
    int r = pos / 18, c = pos % 18;
    int gy = y0 - 1 + r, gx = x0 - 1 + c;
    float v0 = 0.f, v1 = 0.f;
    if (gy >= 0 && gy < IH && gx >= 0 && gx < IW) {
      v0 = fmaxf(fmaf(bf2f(xb[(size_t)(2 * cp) * NPIX + gy * IW + gx]), cA[2 * cp], cB[2 * cp]), 0.f);
      v1 = fmaxf(fmaf(bf2f(xb[(size_t)(2 * cp + 1) * NPIX + gy * IW + gx]), cA[2 * cp + 1], cB[2 * cp + 1]), 0.f);
    }
    unsigned pk = (unsigned)f2bf(v0) | ((unsigned)f2bf(v1) << 16);
    *(unsigned*)(tile + pos * CIS + 2 * cp) = pk;
  }
  __syncthreads();

  floatx4 acc[MPW];
  #pragma unroll
  for (int i = 0; i < MPW; i++) acc[i] = (floatx4){0.f, 0.f, 0.f, 0.f};

  constexpr int NT = CHUNKS * 9;
  const short* wbase = wB + ((size_t)n * NT) * 512 + (lane << 3);
  bf16x8 bfrC, avC[MPW], bfrN, avN[MPW];
  bfrN = *(const bf16x8*)(wbase);
  #pragma unroll
  for (int i = 0; i < MPW; i++)
    avN[i] = *(const bf16x8*)(tile + ((mh * MPW + i) * 18 + lm) * CIS + quad * 8);
  #pragma unroll
  for (int t = 0; t < NT; t++) {
    bfrC = bfrN;
    #pragma unroll
    for (int i = 0; i < MPW; i++) avC[i] = avN[i];
    if (t < NT - 1) {
      int t1 = t + 1;
      int cc1 = t1 / 9, r1 = t1 % 9, ky1 = r1 / 3, kx1 = r1 % 3;
      bfrN = *(const bf16x8*)(wbase + (size_t)t1 * 512);
      #pragma unroll
      for (int i = 0; i < MPW; i++)
        avN[i] = *(const bf16x8*)(tile + ((mh * MPW + i + ky1) * 18 + lm + kx1) * CIS + cc1 * 32 + quad * 8);
    }
    #pragma unroll
    for (int i = 0; i < MPW; i++)
      acc[i] = __builtin_amdgcn_mfma_f32_16x16x32_bf16(avC[i], bfrC, acc[i], 0, 0, 0);
  }
  __syncthreads();   // tile consumed; cout overlays
  #pragma unroll
  for (int i = 0; i < MPW; i++) {
    #pragma unroll
    for (int r = 0; r < 4; r++) {
      int pixel = (mh * MPW + i) * 16 + quad * 4 + r;
      cout[(n * 16 + lm) * 133 + pixel] = acc[i][r];
    }
  }
  __syncthreads();
  unsigned short* ob = out + (size_t)b * CO * NPIX;
  for (int v = tid; v < CO * 128; v += 256) {
    int co = v >> 7, px = v & 127;
    int y = y0 + (px >> 4), x = x0 + (px & 15);
    if (y < IH) ob[(size_t)co * NPIX + y * IW + x] = f2bf(cout[co * 133 + px] + bias[co]);
  }
  if (STATS) {
    constexpr int TPC = 256 / CO;     // threads per channel (8 or 16)
    constexpr int PXT = 128 / TPC;    // pixels per thread
    int col = tid / TPC, seg = tid % TPC;
    float bv = bias[col];
    float sum = 0.f, sq = 0.f;
    #pragma unroll
    for (int k = 0; k < PXT; k++) {
      int p = seg * PXT + k;
      if (y0 + (p >> 4) < IH) {
        float vv = cout[col * 133 + p] + bv;
        sum += vv; sq += vv * vv;
      }
    }
    #pragma unroll
    for (int off = TPC / 2; off > 0; off >>= 1) {
      sum += __shfl_down(sum, off);
      sq  += __shfl_down(sq, off);
    }
    if (seg == 0) {
      atomicAdd(&statsOut[(b * CO + col) * 2], sum);
      atomicAdd(&statsOut[(b * CO + col) * 2 + 1], sq);
    }
  }
}

// ============================================================
// Small direct fp32 3x3 conv, 16x8 tile, bf16 input + fused GN, output
// bf16 (OUT_BF16) or fp32, optional output stats via LDS atomics.
// ============================================================
template <int CI, int CO, int CHPER, bool STATS, bool OUT_BF16>
__global__ __launch_bounds__(256) void convs_kernel(
    const unsigned short* __restrict__ xin, const float* __restrict__ wT,
    const float* __restrict__ bias, const float* __restrict__ statsIn,
    const float* __restrict__ gamma, const float* __restrict__ beta,
    float* __restrict__ statsOut, void* __restrict__ outv) {
  constexpr int OPT = CO / 2;
  const int b = blockIdx.z;
  const int x0 = blockIdx.x * 16, y0 = blockIdx.y * 8;
  __shared__ float tile[CI * 180];
  __shared__ float cA[CI], cB[CI];
  __shared__ float ssum[CO], ssq[CO];
  gn_coef_thread(statsIn, gamma, beta, cA, cB, CI, CHPER, b);
  if (STATS && threadIdx.x < CO) { ssum[threadIdx.x] = 0.f; ssq[threadIdx.x] = 0.f; }
  __syncthreads();
  const unsigned short* xb = xin + (size_t)b * CI * NPIX;
  for (int t = threadIdx.x; t < CI * 180; t += 256) {
    int ci = t / 180, rc = t % 180, r = rc / 18, c = rc % 18;
    int gy = y0 - 1 + r, gx = x0 - 1 + c;
    float v = 0.f;
    if (gy >= 0 && gy < IH && gx >= 0 && gx < IW)
      v = fmaxf(fmaf(bf2f(xb[(size_t)ci * NPIX + gy * IW + gx]), cA[ci], cB[ci]), 0.f);
    tile[t] = v;
  }
  __syncthreads();
  const int t = threadIdx.x;
  const int px = t & 127, og = t >> 7;
  const int pyy = px >> 4, pxx = px & 15;
  const int oc0 = og * OPT;
  const int y = y0 + pyy, x = x0 + pxx;
  float acc[OPT] = {};
  for (int ky = 0; ky < 3; ky++) {
    for (int kx = 0; kx < 3; kx++) {
      const float* wrow = wT + (size_t)((ky * 3 + kx) * CI) * CO + oc0;
      for (int ci = 0; ci < CI; ci++) {
        float v = tile[ci * 180 + (pyy + ky) * 18 + pxx + kx];
        #pragma unroll
        for (int o = 0; o < OPT; o++) acc[o] = fmaf(v, wrow[ci * CO + o], acc[o]);
      }
    }
  }
  if (y < IH) {
    #pragma unroll
    for (int o = 0; o < OPT; o++) {
      float vv = acc[o] + bias[oc0 + o];
      if (OUT_BF16) {
        unsigned short* ob = (unsigned short*)outv + (size_t)b * CO * NPIX;
        ob[(size_t)(oc0 + o) * NPIX + y * IW + x] = f2bf(vv);
      } else {
        float* ob = (float*)outv + (size_t)b * CO * NPIX;
        ob[(size_t)(oc0 + o) * NPIX + y * IW + x] = vv;
      }
      if (STATS) {
        atomicAdd(&ssum[oc0 + o], vv);
        atomicAdd(&ssq[oc0 + o], vv * vv);
      }
    }
  }
  if (STATS) {
    __syncthreads();
    if (threadIdx.x < CO) {
      atomicAdd(&statsOut[(b * CO + threadIdx.x) * 2], ssum[threadIdx.x]);
      atomicAdd(&statsOut[(b * CO + threadIdx.x) * 2 + 1], ssq[threadIdx.x]);
    }
  }
}

// ============================================================
// Joint bilateral 5x5 (reflect), guide fused, global min/max fused.
// ============================================================
__global__ __launch_bounds__(256) void bilateral_kernel(
    const float* __restrict__ f, const float* __restrict__ gt,
    float* __restrict__ out, unsigned* __restrict__ mmbits) {
  const int b = blockIdx.z;
  const int x0 = blockIdx.x * 16, y0 = blockIdx.y * 16;
  __shared__ float gu[20][20], gv[20][20], f0s[20][20], f1s[20][20];
  __shared__ float red[4][4];
  const float* gtb = gt + (size_t)b * 3 * NPIX;
  const float* fb = f + (size_t)b * 2 * NPIX;
  for (int t = threadIdx.x; t < 400; t += 256) {
    int r = t / 20, c = t % 20;
    int gy = y0 - 2 + r, gx = x0 - 2 + c;
    if (gy < 0) gy = -gy;
    if (gy > IH - 1) gy = 2 * (IH - 1) - gy;
    if (gx < 0) gx = -gx;
    if (gx > IW - 1) gx = 2 * (IW - 1) - gx;
    int p = gy * IW + gx;
    float rr = gtb[p], gg = gtb[NPIX + p], bb = gtb[2 * NPIX + p];
    gu[r][c]  = -0.147f * rr - 0.289f * gg + 0.436f * bb;
    gv[r][c]  =  0.615f * rr - 0.515f * gg - 0.100f * bb;
    f0s[r][c] = fb[p];
    f1s[r][c] = fb[NPIX + p];
  }
  __syncthreads();
  const int t = threadIdx.x;
  const int lx = t % 16, ly = t / 16;
  const int y = y0 + ly, x = x0 + lx;
  const bool valid = (y < IH);

  float o0 = 0.f, o1 = 0.f;
  if (valid) {
    float g1v[5];
    float s = 0.f;
    #pragma unroll
    for (int k = 0; k < 5; k++) {
      float a = (float)(k - 2);
      g1v[k] = expf(-a * a / 4.5f);
      s += g1v[k];
    }
    #pragma unroll
    for (int k = 0; k < 5; k++) g1v[k] /= s;
    float cu = gu[ly + 2][lx + 2], cv = gv[ly + 2][lx + 2];
    float num0 = 0.f, num1 = 0.f, den = 0.f;
    #pragma unroll
    for (int dy = 0; dy < 5; dy++) {
      #pragma unroll
      for (int dx = 0; dx < 5; dx++) {
        float du = fabsf(gu[ly + dy][lx + dx] - cu) + fabsf(gv[ly + dy][lx + dx] - cv);
        float wgt = g1v[dy] * g1v[dx] * expf(-50.0f * du * du);
        num0 = fmaf(wgt, f0s[ly + dy][lx + dx], num0);
        num1 = fmaf(wgt, f1s[ly + dy][lx + dx], num1);
        den += wgt;
      }
    }
    o0 = num0 / den; o1 = num1 / den;
    float* ob = out + (size_t)b * 2 * NPIX;
    ob[y * IW + x] = o0;
    ob[NPIX + y * IW + x] = o1;
  }
  float mn0 = valid ? o0 : 1e30f,  mx0 = valid ? o0 : -1e30f;
  float mn1 = valid ? o1 : 1e30f,  mx1 = valid ? o1 : -1e30f;
  #pragma unroll
  for (int off = 32; off > 0; off >>= 1) {
    mn0 = fminf(mn0, __shfl_xor(mn0, off));
    mx0 = fmaxf(mx0, __shfl_xor(mx0, off));
    mn1 = fminf(mn1, __shfl_xor(mn1, off));
    mx1 = fmaxf(mx1, __shfl_xor(mx1, off));
  }
  if ((t & 63) == 0) {
    red[t >> 6][0] = mn0; red[t >> 6][1] = mx0;
    red[t >> 6][2] = mn1; red[t >> 6][3] = mx1;
  }
  __syncthreads();
  if (t == 0) {
    for (int w = 1; w < 4; w++) {
      red[0][0] = fminf(red[0][0], red[w][0]);
      red[0][1] = fmaxf(red[0][1], red[w][1]);
      red[0][2] = fminf(red[0][2], red[w][2]);
      red[0][3] = fmaxf(red[0][3], red[w][3]);
    }
    atomicMax(&mmbits[0], fkey(red[0][1]));   // max0
    atomicMax(&mmbits[1], fkey(red[0][3]));   // max1
    atomicMin(&mmbits[2], fkey(red[0][0]));   // min0
    atomicMin(&mmbits[3], fkey(red[0][2]));   // min1
  }
}

// ============================================================
// Final: rescale U/V from atomic min/max keys, YUV->RGB
// ============================================================
__global__ __launch_bounds__(256) void final_kernel(
    const float* __restrict__ bil, const float* __restrict__ x,
    const unsigned* __restrict__ mmbits, float* __restrict__ out) {
  int i = blockIdx.x * 256 + threadIdx.x;
  if (i >= NB * NPIX) return;
  float mx0 = funkey(mmbits[0]), mx1 = funkey(mmbits[1]);
  float mn0 = funkey(mmbits[2]), mn1 = funkey(mmbits[3]);
  int b = i / NPIX, p = i % NPIX;
  float f0 = bil[(size_t)b * 2 * NPIX + p];
  float f1 = bil[(size_t)b * 2 * NPIX + NPIX + p];
  float U = (f0 - mn0) / (mx0 - mn0 + 1e-6f);
  U = fminf(fmaxf(U, 0.f), 1.f) * 0.872f - 0.436f;
  float V = (f1 - mn1) / (mx1 - mn1 + 1e-6f);
  V = fminf(fmaxf(V, 0.f), 1.f) * 1.23f - 0.615f;
  float Y = x[(size_t)b * NPIX + p];
  float* ob = out + (size_t)b * 3 * NPIX;
  ob[p]            = Y + 1.14f * V;
  ob[NPIX + p]     = Y - 0.396f * U - 0.581f * V;
  ob[2 * NPIX + p] = Y + 2.029f * U;
}

// ============================================================
// launch
// ============================================================
extern "C" void kernel_launch(void* const* d_in, const int* in_sizes, int n_in,
                              void* d_out, int out_size, void* d_ws, size_t ws_size,
                              hipStream_t stream) {
  const float* x   = (const float*)d_in[0];
  const float* gt  = (const float*)d_in[1];
  const float* w1  = (const float*)d_in[2];
  const float* b1  = (const float*)d_in[3];
  const float* g1w = (const float*)d_in[4];
  const float* g1b = (const float*)d_in[5];
  const float* w2  = (const float*)d_in[6];
  const float* b2  = (const float*)d_in[7];
  const float* g2w = (const float*)d_in[8];
  const float* g2b = (const float*)d_in[9];
  const float* w3  = (const float*)d_in[10];
  const float* b3  = (const float*)d_in[11];
  const float* g3w = (const float*)d_in[12];
  const float* g3b = (const float*)d_in[13];
  const float* w4  = (const float*)d_in[14];
  const float* b4  = (const float*)d_in[15];
  const float* g4w = (const float*)d_in[16];
  const float* g4b = (const float*)d_in[17];
  const float* w5  = (const float*)d_in[18];
  const float* b5  = (const float*)d_in[19];
  float* out = (float*)d_out;

  // ---- workspace layout ----
  char* ws = (char*)d_ws;
  float* stats1 = (float*)ws;                  // 512
  float* stats2 = stats1 + 512;                // 256
  float* stats3 = stats2 + 256;                // 128
  float* stats4 = stats3 + 128;                // 64  (ends 960)
  unsigned* mmbits = (unsigned*)(ws + 12288);  // [max0,max1,min0,min1]
  char* base = ws + 16384;
  short* descg = (short*)base;
  size_t descg_shorts = (size_t)NB * 4 * NPIX * 32;       // 70,778,880
  unsigned short* bufB_h = (unsigned short*)base;         // conv2 out 32ch / conv4 out 8ch
  float* c5    = (float*)(base + 36000000);               // conv5 out (2ch fp32)
  float* bilat = (float*)(base + 41000000);               // bilateral out
  short* w1B = descg + descg_shorts;                      // 204800 shorts
  short* w2B = w1B + 204800;                              // 18432
  short* w3B = w2B + 18432;                               // 4608
  float* w4T = (float*)(w3B + 4608);                      // 1152 floats
  float* w5T = w4T + 1152;                                // 144 floats
  unsigned short* bufA_h = (unsigned short*)(w5T + 144);  // conv1 out 64ch / conv3 out 16ch

  hipMemsetAsync(ws, 0, 12304, stream);              // stats + max keys
  hipMemsetAsync(ws + 12296, 0xFF, 8, stream);       // min keys

  prep_kernel<<<896, 256, 0, stream>>>(w1, w2, w3, w4, w5, w1B, w2B, w3B, w4T, w5T);

  sift_desc_kernel<<<dim3(32, 17, NB), 256, 0, stream>>>(x, descg);

  conv1_mfma_kernel<<<dim3(32, 17, NB), 512, 0, stream>>>(descg, w1B, b1, bufA_h, stats1);

  convk3_mfma_kernel<64, 32, 8, true><<<dim3(32, 34, NB), 256, 0, stream>>>(
      bufA_h, w2B, b2, stats1, g1w, g1b, stats2, bufB_h);

  convk3_mfma_kernel<32, 16, 4, true><<<dim3(32, 34, NB), 256, 0, stream>>>(
      bufB_h, w3B, b3, stats2, g2w, g2b, stats3, bufA_h);

  convs_kernel<16, 8, 4, true, true><<<dim3(32, 34, NB), 256, 0, stream>>>(
      bufA_h, w4T, b4, stats3, g3w, g3b, stats4, bufB_h);

  convs_kernel<8, 2, 2, false, false><<<dim3(32, 34, NB), 256, 0, stream>>>(
      bufB_h, w5T, b5, stats4, g4w, g4b, nullptr, c5);

  bilateral_kernel<<<dim3(32, 17, NB), 256, 0, stream>>>(c5, gt, bilat, mmbits);
  final_kernel<<<(NB * NPIX + 255) / 256, 256, 0, stream>>>(bilat, x, mmbits, out);

  (void)in_sizes; (void)n_in; (void)out_size; (void)ws_size;
}

// Round 10
// 1296.585 us; speedup vs baseline: 1.1430x; 1.0026x over previous
//
#include <hip/hip_runtime.h>

// ---------------- problem constants ----------------
constexpr int NB  = 4;
constexpr int IH  = 270;
constexpr int IW  = 512;
constexpr int NPIX = IH * IW;      // 138240
constexpr int PH  = 271;           // pooled height
constexpr int PW  = 513;           // pooled width
constexpr float TWO_PI_F = 6.28318530717958647692f;

typedef short  bf16x8 __attribute__((ext_vector_type(8)));
typedef float floatx4 __attribute__((ext_vector_type(4)));
typedef float floatx16 __attribute__((ext_vector_type(16)));

__device__ inline unsigned short f2bf(float x) {
  union { float f; unsigned u; } un; un.f = x;
  unsigned r = un.u + 0x7fff + ((un.u >> 16) & 1);   // RNE
  return (unsigned short)(r >> 16);
}
__device__ inline float bf2f(unsigned short u) {
  union { unsigned u; float f; } x; x.u = ((unsigned)u) << 16; return x.f;
}
// monotone float<->uint keys for atomic min/max
__device__ inline unsigned fkey(float f) {
  unsigned u = __float_as_uint(f);
  return (u & 0x80000000u) ? ~u : (u | 0x80000000u);
}
__device__ inline float funkey(unsigned k) {
  unsigned u = (k & 0x80000000u) ? (k ^ 0x80000000u) : ~k;
  return __uint_as_float(u);
}
// per-thread GN coef (thread c < C): A,B from fp32 stats
__device__ inline void gn_coef_thread(const float* __restrict__ stats,
                                      const float* __restrict__ gamma,
                                      const float* __restrict__ beta,
                                      float* cA, float* cB, int C, int chper, int b) {
  int c = threadIdx.x;
  if (c < C) {
    int g0 = (c / chper) * chper;
    float S = 0.f, S2 = 0.f;
    for (int k = 0; k < chper; k++) {
      S  += stats[(b * C + g0 + k) * 2];
      S2 += stats[(b * C + g0 + k) * 2 + 1];
    }
    double Nd = (double)chper * NPIX;
    double mu = (double)S / Nd;
    double var = (double)S2 / Nd - mu * mu;
    double rstd = 1.0 / sqrt(var + 1e-5);
    float A = (float)rstd * gamma[c];
    cA[c] = A;
    cB[c] = beta[c] - (float)mu * A;
  }
}

// ============================================================
// Weight prep.
//  - w1: packed for mfma_f32_32x32x16_bf16. frag f = ((ng*4+cc)*25+tap)*2+ks.
//    lane l holds B[k=(l>>5)*8+j][n=l&31]; ci = cc*32 + ks*16 + (l>>5)*8 + j,
//    co = ng*32 + (l&31).
//  - w2/w3: packed for mfma_f32_16x16x32_bf16 (as before).
//  - w4/w5: fp32 repack.
// ============================================================
__device__ inline void mfma_pack32_one(const float* __restrict__ w, short* __restrict__ wB,
                                       int i, int CO, int CI, int KK) {
  int j = i & 7, l = (i >> 3) & 63, f = i >> 9;
  int ks = f & 1; int f2 = f >> 1;
  int tap = f2 % KK; int fc = f2 / KK;
  int cc = fc & 3; int ng = fc >> 2;
  int ci = cc * 32 + ks * 16 + ((l >> 5) << 3) + j;
  int co = ng * 32 + (l & 31);
  float v = (ci < CI && co < CO) ? w[((size_t)co * CI + ci) * KK + tap] : 0.f;
  wB[i] = (short)f2bf(v);
}
__device__ inline void mfma_pack_one(const float* __restrict__ w, short* __restrict__ wB,
                                     int i, int CO, int CI, int KK, int CHUNKS) {
  int j = i & 7, l = (i >> 3) & 63, f = i >> 9;
  int t = f % KK; int fc = f / KK; int cc = fc % CHUNKS; int g = fc / CHUNKS;
  int ci = cc * 32 + ((l >> 4) << 3) + j;
  int co = g * 16 + (l & 15);
  float v = (ci < CI && co < CO) ? w[((size_t)co * CI + ci) * KK + t] : 0.f;
  wB[i] = (short)f2bf(v);
}
__device__ inline void repack_one(const float* __restrict__ w, float* __restrict__ wT,
                                  int i, int CO, int CI, int KK) {
  int o = i / (CI * KK);
  int r = i % (CI * KK);
  int ci = r / KK, kk = r % KK;
  wT[(kk * CI + ci) * CO + o] = w[i];
}
__global__ __launch_bounds__(256) void prep_kernel(
    const float* __restrict__ w1, const float* __restrict__ w2,
    const float* __restrict__ w3, const float* __restrict__ w4,
    const float* __restrict__ w5,
    short* __restrict__ w1B, short* __restrict__ w2B, short* __restrict__ w3B,
    float* __restrict__ w4T, float* __restrict__ w5T) {
  constexpr int N1 = 2 * 4 * 25 * 2 * 512;  // 204800 (32x32 pack)
  constexpr int N2 = 2 * 2 * 9 * 512;       // 18432
  constexpr int N3 = 1 * 1 * 9 * 512;       // 4608
  constexpr int N4 = 8 * 16 * 9;            // 1152
  constexpr int N5 = 2 * 8 * 9;             // 144
  int i = blockIdx.x * 256 + threadIdx.x;
  if (i < N1) { mfma_pack32_one(w1, w1B, i, 64, 128, 25); return; }
  i -= N1;
  if (i < N2) { mfma_pack_one(w2, w2B, i, 32, 64, 9, 2); return; }
  i -= N2;
  if (i < N3) { mfma_pack_one(w3, w3B, i, 16, 32, 9, 1); return; }
  i -= N3;
  if (i < N4) { repack_one(w4, w4T, i, 8, 16, 9); return; }
  i -= N4;
  if (i < N5) { repack_one(w5, w5T, i, 2, 8, 9); return; }
}

// ============================================================
// Fused SIFT front-end: x -> full 128-ch bf16 descriptor, chunk-major
// descg[b][cc][pixel][32ch]. 16x16 tile; grid (32,17,NB), block 256.
// ============================================================
__global__ __launch_bounds__(256) void sift_desc_kernel(
    const float* __restrict__ x, short* __restrict__ descg) {
  const int b = blockIdx.z;
  const int x0 = blockIdx.x * 16, y0 = blockIdx.y * 16;
  __shared__ float xs[24][25];
  __shared__ float wo0[22][23], wo1[22][23];
  __shared__ int   bo0[22][23];
  __shared__ float pooled[8][19][20];
  __shared__ float s1s[256], gs[256];
  const int tid = threadIdx.x;
  const float* xb = x + (size_t)b * NPIX;

  for (int t = tid; t < 576; t += 256) {
    int r = t / 24, c = t % 24;
    int gy = min(max(y0 - 4 + r, 0), IH - 1);
    int gx = min(max(x0 - 4 + c, 0), IW - 1);
    xs[r][c] = xb[gy * IW + gx];
  }
  __syncthreads();

  for (int t = tid; t < 484; t += 256) {
    int r = t / 22, c = t % 22;
    int gy = y0 - 3 + r, gx = x0 - 3 + c;
    float w0 = 0.f, w1v = 0.f; int b0 = 0;
    if (gy >= 0 && gy < IH && gx >= 0 && gx < IW) {
      float gxv = (xs[r + 1][c + 2] - xs[r + 1][c]) * 0.5f;
      float gyv = (xs[r + 2][c + 1] - xs[r][c + 1]) * 0.5f;
      float mag = sqrtf(gxv * gxv + gyv * gyv + 1e-10f);
      float ori = atan2f(gyv, gxv + 1e-10f) + TWO_PI_F;
      float obig = ori * (8.0f / TWO_PI_F);
      float bf = floorf(obig);
      float w1_ = obig - bf;
      w0  = (1.0f - w1_) * mag;
      w1v = w1_ * mag;
      b0  = ((int)bf) & 7;
    }
    wo0[r][c] = w0; wo1[r][c] = w1v; bo0[r][c] = b0;
  }
  __syncthreads();

  const float pwt[4] = {0.25f, 0.75f, 0.75f, 0.25f};
  for (int t = tid; t < 361; t += 256) {
    int pr = t / 19, pc = t % 19;
    int py = y0 - 1 + pr, px = x0 - 1 + pc;
    float acc[8] = {0, 0, 0, 0, 0, 0, 0, 0};
    if (py >= 0 && py < PH && px >= 0 && px < PW) {
      #pragma unroll
      for (int i = 0; i < 4; i++) {
        #pragma unroll
        for (int j = 0; j < 4; j++) {
          float w0 = wo0[pr + i][pc + j], w1v = wo1[pr + i][pc + j];
          int b0 = bo0[pr + i][pc + j];
          int b1i = (b0 + 1) & 7;
          float pw = pwt[i] * pwt[j];
          #pragma unroll
          for (int a = 0; a < 8; a++) {
            float add = (a == b0 ? w0 : 0.f) + (a == b1i ? w1v : 0.f);
            acc[a] = fmaf(pw, add, acc[a]);
          }
        }
      }
    }
    #pragma unroll
    for (int a = 0; a < 8; a++) pooled[a][pr][pc] = acc[a];
  }
  __syncthreads();

  {
    int py = tid >> 4, px = tid & 15;
    int y = y0 + py;
    float s1 = 0.f, g = 0.f;
    if (y < IH) {
      float sum2 = 0.f;
      for (int c = 0; c < 128; c++) {
        int a = c >> 4, i = (c >> 2) & 3, j = c & 3;
        float p = pooled[a][py + i][px + j];
        sum2 = fmaf(p, p, sum2);
      }
      s1 = 1.0f / fmaxf(sqrtf(sum2), 1e-12f);
      float st2 = 0.f, st = 0.f;
      for (int c = 0; c < 128; c++) {
        int a = c >> 4, i = (c >> 2) & 3, j = c & 3;
        float p = pooled[a][py + i][px + j];
        float tv = fminf(p * s1, 0.2f);
        st2 = fmaf(tv, tv, st2);
        st += tv;
      }
      float s2 = 1.0f / fmaxf(sqrtf(st2), 1e-12f);
      float l1 = fmaxf(s2 * st, 1e-12f);
      g = s2 / l1;
    }
    s1s[tid] = s1; gs[tid] = g;
  }
  __syncthreads();

  for (int k = 0; k < 16; k++) {
    int gidx = k * 256 + tid;
    int cc = gidx >> 10, pix = (gidx >> 2) & 255, sub = gidx & 3;
    int py = pix >> 4, px = pix & 15;
    int y = y0 + py;
    if (y >= IH) continue;
    float s1v = s1s[pix], gv = gs[pix];
    int a = cc * 2 + (sub >> 1);
    unsigned short v8[8];
    #pragma unroll
    for (int jj = 0; jj < 8; jj++) {
      int i = (sub * 2 + (jj >> 2)) & 3;
      int j = jj & 3;
      float p = pooled[a][py + i][px + j];
      v8[jj] = f2bf(sqrtf(fminf(p * s1v, 0.2f) * gv + 1e-10f));
    }
    uint4 pk;
    pk.x = (unsigned)v8[0] | ((unsigned)v8[1] << 16);
    pk.y = (unsigned)v8[2] | ((unsigned)v8[3] << 16);
    pk.z = (unsigned)v8[4] | ((unsigned)v8[5] << 16);
    pk.w = (unsigned)v8[6] | ((unsigned)v8[7] << 16);
    size_t base = ((size_t)(b * 4 + cc) * NPIX + (size_t)y * IW + (x0 + px)) * 32 + sub * 8;
    *(uint4*)(descg + base) = pk;
  }
}

// ============================================================
// Conv1 via mfma_f32_32x32x16_bf16, 16x16 tile, 256-thread block.
// 8 m-tiles of 32 px (2 rows each); wave w owns m-tiles {2w,2w+1} x both
// 32-co n-groups (acc = 2x2 floatx16 = 64 AGPR). 50 (tap,kstep) steps per
// chunk with a 2-deep B-fragment ring. Halves LDS A-reads vs 16x16 MFMA
// (each 16B A-frag feeds 32768 FLOP): LDS floor 136 -> 68 us.
// A layout: m=lane&31, k=(lane>>5)*8+j. C/D: col(n)=lane&31,
// row(m)=(reg&3)+8*(reg>>2)+4*(lane>>5) [m74/m101].
// grid (32,17,NB), block 256.
// ============================================================
__global__ __launch_bounds__(256, 2) void conv1_mfma_kernel(
    const short* __restrict__ descg, const short* __restrict__ w1B,
    const float* __restrict__ bias, unsigned short* __restrict__ out,
    float* __restrict__ stats) {
  const int b = blockIdx.z;
  const int x0 = blockIdx.x * 16, y0 = blockIdx.y * 16;
  __shared__ __align__(16) char smem_raw[33408];
  short* desc = (short*)smem_raw;                 // [400 pos][40] bf16
  float* cout = (float*)smem_raw;                 // epilogue [32][261]

  const int tid = threadIdx.x;
  const int wave = tid >> 6, lane = tid & 63;
  const int l31 = lane & 31, lhi = lane >> 5;     // m (A) / n (B) index, k-half

  floatx16 acc[2][2];   // [ng][m-tile]
  #pragma unroll
  for (int j = 0; j < 2; j++)
    #pragma unroll
    for (int i = 0; i < 2; i++)
      #pragma unroll
      for (int r = 0; r < 16; r++) acc[j][i][r] = 0.f;

  for (int cc = 0; cc < 4; cc++) {
    __syncthreads();   // previous chunk consumed
    const short* dg = descg + (size_t)(b * 4 + cc) * NPIX * 32;
    for (int u = tid; u < 1600; u += 256) {        // 400 pos x 4 16B-subs
      int pos = u >> 2, sub = u & 3;
      int r = pos / 20, c = pos % 20;
      int gy = y0 - 2 + r, gx = x0 - 2 + c;
      uint4 val = {0u, 0u, 0u, 0u};
      if (gy >= 0 && gy < IH && gx >= 0 && gx < IW)
        val = *(const uint4*)(dg + ((size_t)gy * IW + gx) * 32 + sub * 8);
      *(uint4*)(desc + pos * 40 + sub * 8) = val;
    }
    __syncthreads();   // desc ready

    const short* wb = w1B + (size_t)cc * 50 * 512 + (lane << 3);
    bf16x8 bfr[2][2];                              // ring slot x ng
    #pragma unroll
    for (int j = 0; j < 2; j++) {
      bfr[0][j] = *(const bf16x8*)(wb + ((size_t)j * 200 + 0) * 512);
      bfr[1][j] = *(const bf16x8*)(wb + ((size_t)j * 200 + 1) * 512);
    }
    #pragma unroll
    for (int t = 0; t < 50; t++) {
      const int tap = t >> 1, ks = t & 1, sl = t & 1;
      const int ky = tap / 5, kx = tap % 5;
      bf16x8 av[2];
      #pragma unroll
      for (int i = 0; i < 2; i++) {
        int mt = wave * 2 + i;
        int r = mt * 2 + (l31 >> 4) + ky;
        int c = (l31 & 15) + kx;
        av[i] = *(const bf16x8*)(desc + (r * 20 + c) * 40 + ks * 16 + (lhi << 3));
      }
      #pragma unroll
      for (int j = 0; j < 2; j++)
        #pragma unroll
        for (int i = 0; i < 2; i++)
          acc[j][i] = __builtin_amdgcn_mfma_f32_32x32x16_bf16(av[i], bfr[sl][j], acc[j][i], 0, 0, 0);
      if (t + 2 < 50) {
        #pragma unroll
        for (int j = 0; j < 2; j++)
          bfr[sl][j] = *(const bf16x8*)(wb + ((size_t)j * 200 + t + 2) * 512);
      }
    }
  }

  // epilogue in two 32-co halves (ng = h): transpose via LDS, bf16 store, GN stats
  unsigned short* ob = out + (size_t)b * 64 * NPIX;
  for (int h = 0; h < 2; h++) {
    __syncthreads();
    #pragma unroll
    for (int i = 0; i < 2; i++) {
      #pragma unroll
      for (int rg = 0; rg < 16; rg++) {
        int row = (rg & 3) + 8 * (rg >> 2) + 4 * lhi;
        int p = (wave * 2 + i) * 32 + row;
        cout[l31 * 261 + p] = acc[h][i][rg];
      }
    }
    __syncthreads();
    for (int v = tid; v < 8192; v += 256) {
      int col = v >> 8, px = v & 255;
      int y = y0 + (px >> 4), x = x0 + (px & 15);
      if (y < IH)
        ob[(size_t)(h * 32 + col) * NPIX + y * IW + x] = f2bf(cout[col * 261 + px] + bias[h * 32 + col]);
    }
    // stats: 32 co x 8 segs (2 rows each)
    int col = tid >> 3, seg = tid & 7;
    int co = h * 32 + col;
    float bv = bias[co];
    float sum = 0.f, sq = 0.f;
    #pragma unroll
    for (int rr = 0; rr < 2; rr++) {
      int row = seg * 2 + rr;
      if (y0 + row < IH) {
        #pragma unroll
        for (int k = 0; k < 16; k++) {
          float vv = cout[col * 261 + row * 16 + k] + bv;
          sum += vv; sq += vv * vv;
        }
      }
    }
    sum += __shfl_down(sum, 4); sq += __shfl_down(sq, 4);
    sum += __shfl_down(sum, 2); sq += __shfl_down(sq, 2);
    sum += __shfl_down(sum, 1); sq += __shfl_down(sq, 1);
    if ((tid & 7) == 0) {
      atomicAdd(&stats[(b * 64 + co) * 2], sum);
      atomicAdd(&stats[(b * 64 + co) * 2 + 1], sq);
    }
  }
}

// ============================================================
// 3x3 conv via MFMA (16x16x32), 16x8 tile, bf16 in/out, fused input-GN +
// output stats, 2-deep B ring. grid (32,34,NB).
// ============================================================
template <int CI, int CO, int CHPER, bool STATS>
__global__ __launch_bounds__(256) void convk3_mfma_kernel(
    const unsigned short* __restrict__ xin, const short* __restrict__ wB,
    const float* __restrict__ bias, const float* __restrict__ statsIn,
    const float* __restrict__ gamma, const float* __restrict__ beta,
    float* __restrict__ statsOut, unsigned short* __restrict__ out) {
  constexpr int CHUNKS = CI / 32;
  constexpr int G = CO / 16;           // co-groups (2 or 1)
  constexpr int MPW = 2 * G;           // m-tiles per wave (4 or 2)
  constexpr int CIS = CI + 8;          // LDS short-stride per position
  constexpr int TILE_B = 180 * CIS * 2;
  constexpr int COUT_B = CO * 133 * 4;
  constexpr int UNION_B = TILE_B > COUT_B ? TILE_B : COUT_B;
  __shared__ __align__(16) char sm[UNION_B + CI * 8];
  short* tile = (short*)sm;
  float* cout = (float*)sm;
  float* cA = (float*)(sm + UNION_B);
  float* cB = cA + CI;

  const int b = blockIdx.z;
  const int x0 = blockIdx.x * 16, y0 = blockIdx.y * 8;
  const int tid = threadIdx.x;
  const int wave = tid >> 6, lane = tid & 63;
  const int quad = lane >> 4, lm = lane & 15;
  const int n = wave % G, mh = wave / G;

  gn_coef_thread(statsIn, gamma, beta, cA, cB, CI, CHPER, b);
  __syncthreads();

  const unsigned short* xb = xin + (size_t)b * CI * NPIX;
  for (int v = tid; v < (CI / 2) * 180; v += 256) {
    int cp = v / 180, pos = v % 180;
    int r = pos / 18, c = pos % 18;
    int gy = y0 - 1 + r, gx = x0 - 1 + c;
    float v0 = 0.f, v1 = 0.f;
    if (gy >= 0 && gy < IH && gx >= 0 && gx < IW) {
      v0 = fmaxf(fmaf(bf2f(xb[(size_t)(2 * cp) * NPIX + gy * IW + gx]), cA[2 * cp], cB[2 * cp]), 0.f);
      v1 = fmaxf(fmaf(bf2f(xb[(size_t)(2 * cp + 1) * NPIX + gy * IW + gx]), cA[2 * cp + 1], cB[2 * cp + 1]), 0.f);
    }
    unsigned pk = (unsigned)f2bf(v0) | ((unsigned)f2bf(v1) << 16);
    *(unsigned*)(tile + pos * CIS + 2 * cp) = pk;
  }
  __syncthreads();

  floatx4 acc[MPW];
  #pragma unroll
  for (int i = 0; i < MPW; i++) acc[i] = (floatx4){0.f, 0.f, 0.f, 0.f};

  constexpr int NT = CHUNKS * 9;
  const short* wbase = wB + ((size_t)n * NT) * 512 + (lane << 3);
  bf16x8 bfr[2];
  bfr[0] = *(const bf16x8*)(wbase);
  bfr[1] = *(const bf16x8*)(wbase + 512);
  #pragma unroll
  for (int t = 0; t < NT; t++) {
    const int sl = t & 1;
    const int cc1 = t / 9, r1 = t % 9, ky = r1 / 3, kx = r1 % 3;
    bf16x8 av[MPW];
    #pragma unroll
    for (int i = 0; i < MPW; i++)
      av[i] = *(const bf16x8*)(tile + ((mh * MPW + i + ky) * 18 + lm + kx) * CIS + cc1 * 32 + quad * 8);
    #pragma unroll
    for (int i = 0; i < MPW; i++)
      acc[i] = __builtin_amdgcn_mfma_f32_16x16x32_bf16(av[i], bfr[sl], acc[i], 0, 0, 0);
    if (t + 2 < NT)
      bfr[sl] = *(const bf16x8*)(wbase + (size_t)(t + 2) * 512);
  }
  __syncthreads();   // tile consumed; cout overlays
  #pragma unroll
  for (int i = 0; i < MPW; i++) {
    #pragma unroll
    for (int r = 0; r < 4; r++) {
      int pixel = (mh * MPW + i) * 16 + quad * 4 + r;
      cout[(n * 16 + lm) * 133 + pixel] = acc[i][r];
    }
  }
  __syncthreads();
  unsigned short* ob = out + (size_t)b * CO * NPIX;
  for (int v = tid; v < CO * 128; v += 256) {
    int co = v >> 7, px = v & 127;
    int y = y0 + (px >> 4), x = x0 + (px & 15);
    if (y < IH) ob[(size_t)co * NPIX + y * IW + x] = f2bf(cout[co * 133 + px] + bias[co]);
  }
  if (STATS) {
    constexpr int TPC = 256 / CO;     // threads per channel (8 or 16)
    constexpr int PXT = 128 / TPC;    // pixels per thread
    int col = tid / TPC, seg = tid % TPC;
    float bv = bias[col];
    float sum = 0.f, sq = 0.f;
    #pragma unroll
    for (int k = 0; k < PXT; k++) {
      int p = seg * PXT + k;
      if (y0 + (p >> 4) < IH) {
        float vv = cout[col * 133 + p] + bv;
        sum += vv; sq += vv * vv;
      }
    }
    #pragma unroll
    for (int off = TPC / 2; off > 0; off >>= 1) {
      sum += __shfl_down(sum, off);
      sq  += __shfl_down(sq, off);
    }
    if (seg == 0) {
      atomicAdd(&statsOut[(b * CO + col) * 2], sum);
      atomicAdd(&statsOut[(b * CO + col) * 2 + 1], sq);
    }
  }
}

// ============================================================
// Small direct fp32 3x3 conv, 16x8 tile, bf16 input + fused GN, output
// bf16 (OUT_BF16) or fp32, optional output stats via LDS atomics.
// ============================================================
template <int CI, int CO, int CHPER, bool STATS, bool OUT_BF16>
__global__ __launch_bounds__(256) void convs_kernel(
    const unsigned short* __restrict__ xin, const float* __restrict__ wT,
    const float* __restrict__ bias, const float* __restrict__ statsIn,
    const float* __restrict__ gamma, const float* __restrict__ beta,
    float* __restrict__ statsOut, void* __restrict__ outv) {
  constexpr int OPT = CO / 2;
  const int b = blockIdx.z;
  const int x0 = blockIdx.x * 16, y0 = blockIdx.y * 8;
  __shared__ float tile[CI * 180];
  __shared__ float cA[CI], cB[CI];
  __shared__ float ssum[CO], ssq[CO];
  gn_coef_thread(statsIn, gamma, beta, cA, cB, CI, CHPER, b);
  if (STATS && threadIdx.x < CO) { ssum[threadIdx.x] = 0.f; ssq[threadIdx.x] = 0.f; }
  __syncthreads();
  const unsigned short* xb = xin + (size_t)b * CI * NPIX;
  for (int t = threadIdx.x; t < CI * 180; t += 256) {
    int ci = t / 180, rc = t % 180, r = rc / 18, c = rc % 18;
    int gy = y0 - 1 + r, gx = x0 - 1 + c;
    float v = 0.f;
    if (gy >= 0 && gy < IH && gx >= 0 && gx < IW)
      v = fmaxf(fmaf(bf2f(xb[(size_t)ci * NPIX + gy * IW + gx]), cA[ci], cB[ci]), 0.f);
    tile[t] = v;
  }
  __syncthreads();
  const int t = threadIdx.x;
  const int px = t & 127, og = t >> 7;
  const int pyy = px >> 4, pxx = px & 15;
  const int oc0 = og * OPT;
  const int y = y0 + pyy, x = x0 + pxx;
  float acc[OPT] = {};
  for (int ky = 0; ky < 3; ky++) {
    for (int kx = 0; kx < 3; kx++) {
      const float* wrow = wT + (size_t)((ky * 3 + kx) * CI) * CO + oc0;
      for (int ci = 0; ci < CI; ci++) {
        float v = tile[ci * 180 + (pyy + ky) * 18 + pxx + kx];
        #pragma unroll
        for (int o = 0; o < OPT; o++) acc[o] = fmaf(v, wrow[ci * CO + o], acc[o]);
      }
    }
  }
  if (y < IH) {
    #pragma unroll
    for (int o = 0; o < OPT; o++) {
      float vv = acc[o] + bias[oc0 + o];
      if (OUT_BF16) {
        unsigned short* ob = (unsigned short*)outv + (size_t)b * CO * NPIX;
        ob[(size_t)(oc0 + o) * NPIX + y * IW + x] = f2bf(vv);
      } else {
        float* ob = (float*)outv + (size_t)b * CO * NPIX;
        ob[(size_t)(oc0 + o) * NPIX + y * IW + x] = vv;
      }
      if (STATS) {
        atomicAdd(&ssum[oc0 + o], vv);
        atomicAdd(&ssq[oc0 + o], vv * vv);
      }
    }
  }
  if (STATS) {
    __syncthreads();
    if (threadIdx.x < CO) {
      atomicAdd(&statsOut[(b * CO + threadIdx.x) * 2], ssum[threadIdx.x]);
      atomicAdd(&statsOut[(b * CO + threadIdx.x) * 2 + 1], ssq[threadIdx.x]);
    }
  }
}

// ============================================================
// Joint bilateral 5x5 (reflect), guide fused, global min/max fused.
// ============================================================
__global__ __launch_bounds__(256) void bilateral_kernel(
    const float* __restrict__ f, const float* __restrict__ gt,
    float* __restrict__ out, unsigned* __restrict__ mmbits) {
  const int b = blockIdx.z;
  const int x0 = blockIdx.x * 16, y0 = blockIdx.y * 16;
  __shared__ float gu[20][20], gv[20][20], f0s[20][20], f1s[20][20];
  __shared__ float red[4][4];
  const float* gtb = gt + (size_t)b * 3 * NPIX;
  const float* fb = f + (size_t)b * 2 * NPIX;
  for (int t = threadIdx.x; t < 400; t += 256) {
    int r = t / 20, c = t % 20;
    int gy = y0 - 2 + r, gx = x0 - 2 + c;
    if (gy < 0) gy = -gy;
    if (gy > IH - 1) gy = 2 * (IH - 1) - gy;
    if (gx < 0) gx = -gx;
    if (gx > IW - 1) gx = 2 * (IW - 1) - gx;
    int p = gy * IW + gx;
    float rr = gtb[p], gg = gtb[NPIX + p], bb = gtb[2 * NPIX + p];
    gu[r][c]  = -0.147f * rr - 0.289f * gg + 0.436f * bb;
    gv[r][c]  =  0.615f * rr - 0.515f * gg - 0.100f * bb;
    f0s[r][c] = fb[p];
    f1s[r][c] = fb[NPIX + p];
  }
  __syncthreads();
  const int t = threadIdx.x;
  const int lx = t % 16, ly = t / 16;
  const int y = y0 + ly, x = x0 + lx;
  const bool valid = (y < IH);

  float o0 = 0.f, o1 = 0.f;
  if (valid) {
    float g1v[5];
    float s = 0.f;
    #pragma unroll
    for (int k = 0; k < 5; k++) {
      float a = (float)(k - 2);
      g1v[k] = expf(-a * a / 4.5f);
      s += g1v[k];
    }
    #pragma unroll
    for (int k = 0; k < 5; k++) g1v[k] /= s;
    float cu = gu[ly + 2][lx + 2], cv = gv[ly + 2][lx + 2];
    float num0 = 0.f, num1 = 0.f, den = 0.f;
    #pragma unroll
    for (int dy = 0; dy < 5; dy++) {
      #pragma unroll
      for (int dx = 0; dx < 5; dx++) {
        float du = fabsf(gu[ly + dy][lx + dx] - cu) + fabsf(gv[ly + dy][lx + dx] - cv);
        float wgt = g1v[dy] * g1v[dx] * expf(-50.0f * du * du);
        num0 = fmaf(wgt, f0s[ly + dy][lx + dx], num0);
        num1 = fmaf(wgt, f1s[ly + dy][lx + dx], num1);
        den += wgt;
      }
    }
    o0 = num0 / den; o1 = num1 / den;
    float* ob = out + (size_t)b * 2 * NPIX;
    ob[y * IW + x] = o0;
    ob[NPIX + y * IW + x] = o1;
  }
  float mn0 = valid ? o0 : 1e30f,  mx0 = valid ? o0 : -1e30f;
  float mn1 = valid ? o1 : 1e30f,  mx1 = valid ? o1 : -1e30f;
  #pragma unroll
  for (int off = 32; off > 0; off >>= 1) {
    mn0 = fminf(mn0, __shfl_xor(mn0, off));
    mx0 = fmaxf(mx0, __shfl_xor(mx0, off));
    mn1 = fminf(mn1, __shfl_xor(mn1, off));
    mx1 = fmaxf(mx1, __shfl_xor(mx1, off));
  }
  if ((t & 63) == 0) {
    red[t >> 6][0] = mn0; red[t >> 6][1] = mx0;
    red[t >> 6][2] = mn1; red[t >> 6][3] = mx1;
  }
  __syncthreads();
  if (t == 0) {
    for (int w = 1; w < 4; w++) {
      red[0][0] = fminf(red[0][0], red[w][0]);
      red[0][1] = fmaxf(red[0][1], red[w][1]);
      red[0][2] = fminf(red[0][2], red[w][2]);
      red[0][3] = fmaxf(red[0][3], red[w][3]);
    }
    atomicMax(&mmbits[0], fkey(red[0][1]));   // max0
    atomicMax(&mmbits[1], fkey(red[0][3]));   // max1
    atomicMin(&mmbits[2], fkey(red[0][0]));   // min0
    atomicMin(&mmbits[3], fkey(red[0][2]));   // min1
  }
}

// ============================================================
// Final: rescale U/V from atomic min/max keys, YUV->RGB
// ============================================================
__global__ __launch_bounds__(256) void final_kernel(
    const float* __restrict__ bil, const float* __restrict__ x,
    const unsigned* __restrict__ mmbits, float* __restrict__ out) {
  int i = blockIdx.x * 256 + threadIdx.x;
  if (i >= NB * NPIX) return;
  float mx0 = funkey(mmbits[0]), mx1 = funkey(mmbits[1]);
  float mn0 = funkey(mmbits[2]), mn1 = funkey(mmbits[3]);
  int b = i / NPIX, p = i % NPIX;
  float f0 = bil[(size_t)b * 2 * NPIX + p];
  float f1 = bil[(size_t)b * 2 * NPIX + NPIX + p];
  float U = (f0 - mn0) / (mx0 - mn0 + 1e-6f);
  U = fminf(fmaxf(U, 0.f), 1.f) * 0.872f - 0.436f;
  float V = (f1 - mn1) / (mx1 - mn1 + 1e-6f);
  V = fminf(fmaxf(V, 0.f), 1.f) * 1.23f - 0.615f;
  float Y = x[(size_t)b * NPIX + p];
  float* ob = out + (size_t)b * 3 * NPIX;
  ob[p]            = Y + 1.14f * V;
  ob[NPIX + p]     = Y - 0.396f * U - 0.581f * V;
  ob[2 * NPIX + p] = Y + 2.029f * U;
}

// ============================================================
// launch
// ============================================================
extern "C" void kernel_launch(void* const* d_in, const int* in_sizes, int n_in,
                              void* d_out, int out_size, void* d_ws, size_t ws_size,
                              hipStream_t stream) {
  const float* x   = (const float*)d_in[0];
  const float* gt  = (const float*)d_in[1];
  const float* w1  = (const float*)d_in[2];
  const float* b1  = (const float*)d_in[3];
  const float* g1w = (const float*)d_in[4];
  const float* g1b = (const float*)d_in[5];
  const float* w2  = (const float*)d_in[6];
  const float* b2  = (const float*)d_in[7];
  const float* g2w = (const float*)d_in[8];
  const float* g2b = (const float*)d_in[9];
  const float* w3  = (const float*)d_in[10];
  const float* b3  = (const float*)d_in[11];
  const float* g3w = (const float*)d_in[12];
  const float* g3b = (const float*)d_in[13];
  const float* w4  = (const float*)d_in[14];
  const float* b4  = (const float*)d_in[15];
  const float* g4w = (const float*)d_in[16];
  const float* g4b = (const float*)d_in[17];
  const float* w5  = (const float*)d_in[18];
  const float* b5  = (const float*)d_in[19];
  float* out = (float*)d_out;

  // ---- workspace layout ----
  char* ws = (char*)d_ws;
  float* stats1 = (float*)ws;                  // 512
  float* stats2 = stats1 + 512;                // 256
  float* stats3 = stats2 + 256;                // 128
  float* stats4 = stats3 + 128;                // 64  (ends 960)
  unsigned* mmbits = (unsigned*)(ws + 12288);  // [max0,max1,min0,min1]
  char* base = ws + 16384;
  short* descg = (short*)base;
  size_t descg_shorts = (size_t)NB * 4 * NPIX * 32;       // 70,778,880
  unsigned short* bufB_h = (unsigned short*)base;         // conv2 out 32ch / conv4 out 8ch
  float* c5    = (float*)(base + 36000000);               // conv5 out (2ch fp32)
  float* bilat = (float*)(base + 41000000);               // bilateral out
  short* w1B = descg + descg_shorts;                      // 204800 shorts
  short* w2B = w1B + 204800;                              // 18432
  short* w3B = w2B + 18432;                               // 4608
  float* w4T = (float*)(w3B + 4608);                      // 1152 floats
  float* w5T = w4T + 1152;                                // 144 floats
  unsigned short* bufA_h = (unsigned short*)(w5T + 144);  // conv1 out 64ch / conv3 out 16ch

  hipMemsetAsync(ws, 0, 12304, stream);              // stats + max keys
  hipMemsetAsync(ws + 12296, 0xFF, 8, stream);       // min keys

  prep_kernel<<<896, 256, 0, stream>>>(w1, w2, w3, w4, w5, w1B, w2B, w3B, w4T, w5T);

  sift_desc_kernel<<<dim3(32, 17, NB), 256, 0, stream>>>(x, descg);

  conv1_mfma_kernel<<<dim3(32, 17, NB), 256, 0, stream>>>(descg, w1B, b1, bufA_h, stats1);

  convk3_mfma_kernel<64, 32, 8, true><<<dim3(32, 34, NB), 256, 0, stream>>>(
      bufA_h, w2B, b2, stats1, g1w, g1b, stats2, bufB_h);

  convk3_mfma_kernel<32, 16, 4, true><<<dim3(32, 34, NB), 256, 0, stream>>>(
      bufB_h, w3B, b3, stats2, g2w, g2b, stats3, bufA_h);

  convs_kernel<16, 8, 4, true, true><<<dim3(32, 34, NB), 256, 0, stream>>>(
      bufA_h, w4T, b4, stats3, g3w, g3b, stats4, bufB_h);

  convs_kernel<8, 2, 2, false, false><<<dim3(32, 34, NB), 256, 0, stream>>>(
      bufB_h, w5T, b5, stats4, g4w, g4b, nullptr, c5);

  bilateral_kernel<<<dim3(32, 17, NB), 256, 0, stream>>>(c5, gt, bilat, mmbits);
  final_kernel<<<(NB * NPIX + 255) / 256, 256, 0, stream>>>(bilat, x, mmbits, out);

  (void)in_sizes; (void)n_in; (void)out_size; (void)ws_size;
}